// Round 1
// baseline (1740.121 us; speedup 1.0000x reference)
//
#include <hip/hip_runtime.h>

#pragma clang fp contract(off)

#define NB 8
#define KSEL 6000
#define KPAD 6016
#define PROP 1000
#define EQCAP 8192

// ws layout (bytes)
#define OFF_HIST1 0u          // 8*4096*4 = 131072
#define OFF_HIST2 131072u     // 8*4096*4
#define OFF_HIST3 262144u     // 8*256*4 = 8192
#define OFF_CTRL  270336u     // 8*64 = 512
#define OFF_SEL   270848u     // 8*6016*8 = 385024
#define OFF_EQ    655872u     // 8*8192*4 = 262144
#define OFF_SIDX  918016u     // 8*6016*4 = 192512
#define OFF_BOX   1110528u    // 8*6016*16 = 770048 -> end 1880576

struct Ctrl {
  unsigned t1, rem1, t2, rem2, thr, needEq, selCount, eqCount, total;
  unsigned pad[7];
};

__global__ __launch_bounds__(256) void zero_kernel(unsigned* p, int n) {
  int i = blockIdx.x * 256 + threadIdx.x;
  if (i < n) p[i] = 0u;
}

// phase 1: bin = bits>>20 (4096 bins); phase 2: mid 12 bits within t1; phase 3: low 8 bits within (t1,t2)
__global__ __launch_bounds__(256) void hist_kernel(int phase, const float* __restrict__ probs,
                                                   unsigned* __restrict__ hist,
                                                   const Ctrl* __restrict__ ctrl, int N) {
  __shared__ unsigned lh[4096];
  const int b = blockIdx.y;
  const int nb = (phase == 3) ? 256 : 4096;
  for (int k = threadIdx.x; k < nb; k += 256) lh[k] = 0u;
  unsigned t1 = 0, pre24 = 0;
  if (phase == 2) t1 = ctrl[b].t1;
  if (phase == 3) pre24 = (ctrl[b].t1 << 12) | ctrl[b].t2;
  __syncthreads();
  const int start = blockIdx.x * 16384;
  const int end = min(start + 16384, N);
  for (int i = start + (int)threadIdx.x; i < end; i += 256) {
    const unsigned bits = __float_as_uint(probs[(size_t)(b * N + i) * 2 + 1]);
    if (phase == 1) atomicAdd(&lh[bits >> 20], 1u);
    else if (phase == 2) { if ((bits >> 20) == t1) atomicAdd(&lh[(bits >> 8) & 0xFFFu], 1u); }
    else { if ((bits >> 8) == pre24) atomicAdd(&lh[bits & 0xFFu], 1u); }
  }
  __syncthreads();
  for (int k = threadIdx.x; k < nb; k += 256) {
    const unsigned v = lh[k];
    if (v) atomicAdd(&hist[b * nb + k], v);
  }
}

// one wave per image: descending cumulative scan, find threshold bin
__global__ __launch_bounds__(64) void scan_kernel(int phase, const unsigned* __restrict__ hist,
                                                  Ctrl* __restrict__ ctrl) {
  const int b = blockIdx.x;
  const int lane = threadIdx.x;
  const int nb = (phase == 3) ? 256 : 4096;
  const int chunks = nb >> 6;
  const unsigned target = (phase == 1) ? 6000u : ((phase == 2) ? ctrl[b].rem1 : ctrl[b].rem2);
  const unsigned* h = hist + b * nb;
  const int topbin = nb - 1 - lane * chunks;
  unsigned mysum = 0;
  for (int c = 0; c < chunks; c++) mysum += h[topbin - c];
  unsigned cum = mysum;
  for (int off = 1; off < 64; off <<= 1) {
    const unsigned v = __shfl_up(cum, off, 64);
    if (lane >= off) cum += v;
  }
  const unsigned prev = cum - mysum;
  if (prev < target && cum >= target) {
    unsigned c2 = prev;
    for (int c = 0; c < chunks; c++) {
      const int bin = topbin - c;
      const unsigned hv = h[bin];
      if (c2 + hv >= target) {
        const unsigned rem = target - c2;
        if (phase == 1) { ctrl[b].t1 = (unsigned)bin; ctrl[b].rem1 = rem; }
        else if (phase == 2) { ctrl[b].t2 = (unsigned)bin; ctrl[b].rem2 = rem; }
        else {
          ctrl[b].thr = (ctrl[b].t1 << 20) | (ctrl[b].t2 << 8) | (unsigned)bin;
          ctrl[b].needEq = rem;
        }
        break;
      }
      c2 += hv;
    }
  }
}

__global__ __launch_bounds__(256) void compact_kernel(const float* __restrict__ probs, Ctrl* __restrict__ ctrl,
                                                      unsigned long long* __restrict__ sel,
                                                      unsigned* __restrict__ eqBuf, int N) {
  const int b = blockIdx.y;
  const unsigned THR = ctrl[b].thr;
  const int start = blockIdx.x * 16384;
  const int end = min(start + 16384, N);
  const int lane = threadIdx.x & 63;
  const int iters = (end - start + 255) / 256;
  for (int it = 0; it < iters; it++) {
    const int i = start + it * 256 + (int)threadIdx.x;
    const bool v = i < end;
    unsigned bits = 0u;
    if (v) bits = __float_as_uint(probs[(size_t)(b * N + i) * 2 + 1]);
    const bool gt = v && (bits > THR);
    const bool eq = v && (bits == THR);
    const unsigned long long mg = __ballot(gt);
    if (mg) {
      const int leader = __builtin_ctzll(mg);
      unsigned base = 0;
      if (lane == leader) base = atomicAdd(&ctrl[b].selCount, (unsigned)__builtin_popcountll(mg));
      base = (unsigned)__shfl((int)base, leader, 64);
      if (gt) {
        const int rank = __builtin_popcountll(mg & ((1ull << lane) - 1ull));
        const unsigned pos = base + (unsigned)rank;
        if (pos < (unsigned)KPAD) sel[b * KPAD + pos] = ((unsigned long long)bits << 32) | (unsigned)i;
      }
    }
    const unsigned long long me = __ballot(eq);
    if (me) {
      const int leader = __builtin_ctzll(me);
      unsigned base = 0;
      if (lane == leader) base = atomicAdd(&ctrl[b].eqCount, (unsigned)__builtin_popcountll(me));
      base = (unsigned)__shfl((int)base, leader, 64);
      if (eq) {
        const int rank = __builtin_popcountll(me & ((1ull << lane) - 1ull));
        const unsigned pos = base + (unsigned)rank;
        if (pos < (unsigned)EQCAP) eqBuf[b * EQCAP + pos] = (unsigned)i;
      }
    }
  }
}

// resolve ties at the exact threshold: take lowest indices
__global__ __launch_bounds__(256) void eqres_kernel(Ctrl* __restrict__ ctrl, const unsigned* __restrict__ eqBuf,
                                                    unsigned long long* __restrict__ sel) {
  __shared__ unsigned si[EQCAP];
  const int b = blockIdx.x;
  const unsigned need = ctrl[b].needEq;
  unsigned cnt = ctrl[b].eqCount; if (cnt > EQCAP) cnt = EQCAP;
  const unsigned base = ctrl[b].selCount;
  const unsigned long long thrHi = ((unsigned long long)ctrl[b].thr) << 32;
  if (cnt <= need) {
    for (unsigned e = threadIdx.x; e < cnt; e += 256)
      sel[b * KPAD + base + e] = thrHi | (unsigned long long)eqBuf[b * EQCAP + e];
    if (threadIdx.x == 0) ctrl[b].total = base + cnt;
  } else {
    for (int k = threadIdx.x; k < EQCAP; k += 256)
      si[k] = (k < (int)cnt) ? eqBuf[b * EQCAP + k] : 0xFFFFFFFFu;
    __syncthreads();
    for (int k = 2; k <= EQCAP; k <<= 1)
      for (int j = k >> 1; j > 0; j >>= 1) {
        for (int idx = threadIdx.x; idx < EQCAP; idx += 256) {
          const int p = idx ^ j;
          if (p > idx) {
            const unsigned a = si[idx], c = si[p];
            const bool up = ((idx & k) == 0);
            if ((a > c) == up) { si[idx] = c; si[p] = a; }
          }
        }
        __syncthreads();
      }
    for (unsigned e = threadIdx.x; e < need; e += 256)
      sel[b * KPAD + base + e] = thrHi | (unsigned long long)si[e];
    if (threadIdx.x == 0) ctrl[b].total = base + need;
  }
}

// full sort of the 6000 selected: key = (scorebits, 0xFFFFFFFF - idx), descending == lax.top_k order
__global__ __launch_bounds__(1024) void sort_kernel(const Ctrl* __restrict__ ctrl,
                                                    const unsigned long long* __restrict__ sel,
                                                    unsigned* __restrict__ sidx) {
  __shared__ unsigned long long skey[8192];  // 64 KiB
  const int b = blockIdx.x;
  int total = (int)ctrl[b].total; if (total > KSEL) total = KSEL;
  for (int i = threadIdx.x; i < 8192; i += 1024) {
    unsigned long long kp = ~0ull;
    if (i < total) {
      const unsigned long long e = sel[b * KPAD + i];
      const unsigned bits = (unsigned)(e >> 32);
      const unsigned idx = (unsigned)e;
      const unsigned long long key = ((unsigned long long)bits << 32) | (unsigned long long)(0xFFFFFFFFu - idx);
      kp = ~key;  // sort ascending on ~key == descending on key
    }
    skey[i] = kp;
  }
  __syncthreads();
  for (int k = 2; k <= 8192; k <<= 1)
    for (int j = k >> 1; j > 0; j >>= 1) {
      for (int i = threadIdx.x; i < 8192; i += 1024) {
        const int p = i ^ j;
        if (p > i) {
          const unsigned long long a = skey[i], c = skey[p];
          const bool up = ((i & k) == 0);
          if ((a > c) == up) { skey[i] = c; skey[p] = a; }
        }
      }
      __syncthreads();
    }
  for (int r = threadIdx.x; r < KSEL; r += 1024) {
    const unsigned long long key = ~skey[r];
    sidx[b * KPAD + r] = 0xFFFFFFFFu - (unsigned)(key & 0xFFFFFFFFull);
  }
}

__global__ __launch_bounds__(256) void decode_kernel(const float* __restrict__ anchors,
                                                     const float* __restrict__ bbox,
                                                     const unsigned* __restrict__ sidx,
                                                     float4* __restrict__ boxes, int N) {
  const int b = blockIdx.y;
  const int j = blockIdx.x * 256 + (int)threadIdx.x;
  if (j >= KSEL) return;
  unsigned idx = sidx[b * KPAD + j];
  if (idx >= (unsigned)N) idx = 0;  // safety
  const float4 A = ((const float4*)anchors)[(size_t)b * N + idx];
  const float4 R = ((const float4*)bbox)[(size_t)b * N + idx];
  // exact f32 replication of reference (contract(off) is file-scope)
  const float d0 = R.x * 0.1f, d1 = R.y * 0.1f, d2 = R.z * 0.2f, d3 = R.w * 0.2f;
  const float h = A.z - A.x;
  const float w = A.w - A.y;
  const float cy = A.x + 0.5f * h + d0 * h;
  const float cx = A.y + 0.5f * w + d1 * w;
  const float e2 = (float)exp((double)d2);  // correctly-rounded f32 exp
  const float e3 = (float)exp((double)d3);
  const float h2 = h * e2;
  const float w2 = w * e3;
  float y1 = cy - 0.5f * h2;
  float x1 = cx - 0.5f * w2;
  float y2 = y1 + h2;
  float x2 = x1 + w2;
  y1 = fminf(fmaxf(y1, 0.0f), 1.0f);
  x1 = fminf(fmaxf(x1, 0.0f), 1.0f);
  y2 = fminf(fmaxf(y2, 0.0f), 1.0f);
  x2 = fminf(fmaxf(x2, 0.0f), 1.0f);
  boxes[b * KPAD + j] = make_float4(y1, x1, y2, x2);
}

// exact greedy NMS, one block per image, boxes in registers (static-indexed), LDS suppression bitmask
__global__ __launch_bounds__(1024) void nms_kernel(const float4* __restrict__ boxes, float* __restrict__ out) {
  const int b = blockIdx.x;
  const int tid = threadIdx.x;
  const float4* bx = boxes + b * KPAD;
  __shared__ unsigned long long smask[94];
  __shared__ float4 shb;
  __shared__ float sha;
  float4 box[6]; float area[6];
  unsigned aliveM = 0;
#pragma unroll
  for (int s = 0; s < 6; s++) {
    const int j = tid + (s << 10);
    if (j < KSEL) {
      const float4 v = bx[j];
      box[s] = v;
      area[s] = (v.z - v.x) * (v.w - v.y);  // matches reference area formula
      aliveM |= (1u << s);
    } else {
      box[s] = make_float4(0.f, 0.f, 0.f, 0.f);
      area[s] = 0.f;
    }
  }
  if (tid < 94) smask[tid] = (tid == 93) ? (~0ull << 48) : 0ull;  // pad indices 6000..6015 suppressed
  if (tid == 0) { shb = box[0]; sha = area[0]; }  // head=0 owner is tid 0, slot 0
  int head = 0;
  int written = 0;
  float* outB = out + b * (PROP * 4);
  // M = 0.7f + 2^-25: round(inter/denom) > 0.7f  <=>  inter >= M*denom (exact in double)
  const double M = 0.7000000178813934326171875;
  for (int sel = 0; sel < PROP; sel++) {
    __syncthreads();  // A: shb/sha visible; prior mask scans done
    const float4 hb = shb; const float ha = sha;
    if (tid == 0) {
      outB[sel * 4 + 0] = hb.x; outB[sel * 4 + 1] = hb.y;
      outB[sel * 4 + 2] = hb.z; outB[sel * 4 + 3] = hb.w;
    }
#pragma unroll
    for (int s = 0; s < 6; s++) {
      if (aliveM & (1u << s)) {
        const float4 v = box[s];
        const float iy1 = fmaxf(hb.x, v.x);
        const float ix1 = fmaxf(hb.y, v.y);
        const float iy2 = fminf(hb.z, v.z);
        const float ix2 = fminf(hb.w, v.w);
        const float dy = fmaxf(iy2 - iy1, 0.0f);
        const float dx = fmaxf(ix2 - ix1, 0.0f);
        const float inter = dy * dx;
        const float denom = ha + area[s] - inter + 1e-12f;  // ((ha+a)-inter)+1e-12, like reference
        const int j = tid + (s << 10);
        if ((j == head) || ((double)inter >= M * (double)denom)) {
          aliveM &= ~(1u << s);
          atomicOr(&smask[j >> 6], 1ull << (j & 63));
        }
      }
    }
    written = sel + 1;
    __syncthreads();  // B: mask updates visible
    int hh = head + 1;
    while (hh < 6016) {
      const unsigned long long wmask = smask[hh >> 6];
      const unsigned long long inv = (~wmask) >> (hh & 63);
      if (inv) { hh += __builtin_ctzll(inv); break; }
      hh = ((hh >> 6) + 1) << 6;
    }
    head = hh;
    if (head >= KSEL) break;  // exhausted: rest are zeros (matches valid=False padding)
    if (tid == (head & 1023)) {
      const int s = head >> 10;
      float4 t = box[0]; float a = area[0];
#pragma unroll
      for (int q = 1; q < 6; q++) if (s == q) { t = box[q]; a = area[q]; }
      shb = t; sha = a;
    }
  }
  const int rem = (PROP - written) * 4;
  for (int u = tid; u < rem; u += 1024) outB[written * 4 + u] = 0.0f;
}

extern "C" void kernel_launch(void* const* d_in, const int* in_sizes, int n_in,
                              void* d_out, int out_size, void* d_ws, size_t ws_size,
                              hipStream_t stream) {
  (void)n_in; (void)out_size; (void)ws_size;
  const float* probs = (const float*)d_in[0];
  const float* bbox = (const float*)d_in[1];
  const float* anchors = (const float*)d_in[2];
  float* out = (float*)d_out;
  char* ws = (char*)d_ws;
  const int N = in_sizes[0] / (NB * 2);  // 261888

  unsigned* hist1 = (unsigned*)(ws + OFF_HIST1);
  unsigned* hist2 = (unsigned*)(ws + OFF_HIST2);
  unsigned* hist3 = (unsigned*)(ws + OFF_HIST3);
  Ctrl* ctrl = (Ctrl*)(ws + OFF_CTRL);
  unsigned long long* sel = (unsigned long long*)(ws + OFF_SEL);
  unsigned* eqBuf = (unsigned*)(ws + OFF_EQ);
  unsigned* sidx = (unsigned*)(ws + OFF_SIDX);
  float4* boxes = (float4*)(ws + OFF_BOX);

  const int zeroN = (int)(OFF_SEL / 4);  // hist1+hist2+hist3+ctrl
  zero_kernel<<<dim3((zeroN + 255) / 256), dim3(256), 0, stream>>>((unsigned*)ws, zeroN);

  const int gx = (N + 16383) / 16384;
  hist_kernel<<<dim3(gx, NB), dim3(256), 0, stream>>>(1, probs, hist1, ctrl, N);
  scan_kernel<<<dim3(NB), dim3(64), 0, stream>>>(1, hist1, ctrl);
  hist_kernel<<<dim3(gx, NB), dim3(256), 0, stream>>>(2, probs, hist2, ctrl, N);
  scan_kernel<<<dim3(NB), dim3(64), 0, stream>>>(2, hist2, ctrl);
  hist_kernel<<<dim3(gx, NB), dim3(256), 0, stream>>>(3, probs, hist3, ctrl, N);
  scan_kernel<<<dim3(NB), dim3(64), 0, stream>>>(3, hist3, ctrl);
  compact_kernel<<<dim3(gx, NB), dim3(256), 0, stream>>>(probs, ctrl, sel, eqBuf, N);
  eqres_kernel<<<dim3(NB), dim3(256), 0, stream>>>(ctrl, eqBuf, sel);
  sort_kernel<<<dim3(NB), dim3(1024), 0, stream>>>(ctrl, sel, sidx);
  decode_kernel<<<dim3((KSEL + 255) / 256, NB), dim3(256), 0, stream>>>(anchors, bbox, sidx, boxes, N);
  nms_kernel<<<dim3(NB), dim3(1024), 0, stream>>>(boxes, out);
}

// Round 2
// 1492.690 us; speedup vs baseline: 1.1658x; 1.1658x over previous
//
#include <hip/hip_runtime.h>

#pragma clang fp contract(off)

#define NB 8
#define KSEL 6000
#define KPAD 6016
#define PROP 1000
#define EQCAP 8192

// ws layout (bytes)
#define OFF_HIST1 0u          // 8*4096*4 = 131072
#define OFF_HIST2 131072u     // 8*4096*4
#define OFF_HIST3 262144u     // 8*256*4 = 8192
#define OFF_CTRL  270336u     // 8*64 = 512
#define OFF_SEL   270848u     // 8*6016*8 = 385024
#define OFF_EQ    655872u     // 8*8192*4 = 262144
#define OFF_SIDX  918016u     // 8*6016*4 = 192512
#define OFF_BOX   1110528u    // 8*6016*16 = 770048 -> end 1880576

struct Ctrl {
  unsigned t1, rem1, t2, rem2, thr, needEq, selCount, eqCount, total;
  unsigned pad[7];
};

__global__ __launch_bounds__(256) void zero_kernel(unsigned* p, int n) {
  int i = blockIdx.x * 256 + threadIdx.x;
  if (i < n) p[i] = 0u;
}

// phase 1: bin = bits>>20 (4096 bins); phase 2: mid 12 bits within t1; phase 3: low 8 bits within (t1,t2)
__global__ __launch_bounds__(256) void hist_kernel(int phase, const float* __restrict__ probs,
                                                   unsigned* __restrict__ hist,
                                                   const Ctrl* __restrict__ ctrl, int N) {
  __shared__ unsigned lh[4096];
  const int b = blockIdx.y;
  const int nb = (phase == 3) ? 256 : 4096;
  for (int k = threadIdx.x; k < nb; k += 256) lh[k] = 0u;
  unsigned t1 = 0, pre24 = 0;
  if (phase == 2) t1 = ctrl[b].t1;
  if (phase == 3) pre24 = (ctrl[b].t1 << 12) | ctrl[b].t2;
  __syncthreads();
  const int start = blockIdx.x * 16384;
  const int end = min(start + 16384, N);
  for (int i = start + (int)threadIdx.x; i < end; i += 256) {
    const unsigned bits = __float_as_uint(probs[(size_t)(b * N + i) * 2 + 1]);
    if (phase == 1) atomicAdd(&lh[bits >> 20], 1u);
    else if (phase == 2) { if ((bits >> 20) == t1) atomicAdd(&lh[(bits >> 8) & 0xFFFu], 1u); }
    else { if ((bits >> 8) == pre24) atomicAdd(&lh[bits & 0xFFu], 1u); }
  }
  __syncthreads();
  for (int k = threadIdx.x; k < nb; k += 256) {
    const unsigned v = lh[k];
    if (v) atomicAdd(&hist[b * nb + k], v);
  }
}

// one wave per image: descending cumulative scan, find threshold bin
__global__ __launch_bounds__(64) void scan_kernel(int phase, const unsigned* __restrict__ hist,
                                                  Ctrl* __restrict__ ctrl) {
  const int b = blockIdx.x;
  const int lane = threadIdx.x;
  const int nb = (phase == 3) ? 256 : 4096;
  const int chunks = nb >> 6;
  const unsigned target = (phase == 1) ? 6000u : ((phase == 2) ? ctrl[b].rem1 : ctrl[b].rem2);
  const unsigned* h = hist + b * nb;
  const int topbin = nb - 1 - lane * chunks;
  unsigned mysum = 0;
  for (int c = 0; c < chunks; c++) mysum += h[topbin - c];
  unsigned cum = mysum;
  for (int off = 1; off < 64; off <<= 1) {
    const unsigned v = __shfl_up(cum, off, 64);
    if (lane >= off) cum += v;
  }
  const unsigned prev = cum - mysum;
  if (prev < target && cum >= target) {
    unsigned c2 = prev;
    for (int c = 0; c < chunks; c++) {
      const int bin = topbin - c;
      const unsigned hv = h[bin];
      if (c2 + hv >= target) {
        const unsigned rem = target - c2;
        if (phase == 1) { ctrl[b].t1 = (unsigned)bin; ctrl[b].rem1 = rem; }
        else if (phase == 2) { ctrl[b].t2 = (unsigned)bin; ctrl[b].rem2 = rem; }
        else {
          ctrl[b].thr = (ctrl[b].t1 << 20) | (ctrl[b].t2 << 8) | (unsigned)bin;
          ctrl[b].needEq = rem;
        }
        break;
      }
      c2 += hv;
    }
  }
}

__global__ __launch_bounds__(256) void compact_kernel(const float* __restrict__ probs, Ctrl* __restrict__ ctrl,
                                                      unsigned long long* __restrict__ sel,
                                                      unsigned* __restrict__ eqBuf, int N) {
  const int b = blockIdx.y;
  const unsigned THR = ctrl[b].thr;
  const int start = blockIdx.x * 16384;
  const int end = min(start + 16384, N);
  const int lane = threadIdx.x & 63;
  const int iters = (end - start + 255) / 256;
  for (int it = 0; it < iters; it++) {
    const int i = start + it * 256 + (int)threadIdx.x;
    const bool v = i < end;
    unsigned bits = 0u;
    if (v) bits = __float_as_uint(probs[(size_t)(b * N + i) * 2 + 1]);
    const bool gt = v && (bits > THR);
    const bool eq = v && (bits == THR);
    const unsigned long long mg = __ballot(gt);
    if (mg) {
      const int leader = __builtin_ctzll(mg);
      unsigned base = 0;
      if (lane == leader) base = atomicAdd(&ctrl[b].selCount, (unsigned)__builtin_popcountll(mg));
      base = (unsigned)__shfl((int)base, leader, 64);
      if (gt) {
        const int rank = __builtin_popcountll(mg & ((1ull << lane) - 1ull));
        const unsigned pos = base + (unsigned)rank;
        if (pos < (unsigned)KPAD) sel[b * KPAD + pos] = ((unsigned long long)bits << 32) | (unsigned)i;
      }
    }
    const unsigned long long me = __ballot(eq);
    if (me) {
      const int leader = __builtin_ctzll(me);
      unsigned base = 0;
      if (lane == leader) base = atomicAdd(&ctrl[b].eqCount, (unsigned)__builtin_popcountll(me));
      base = (unsigned)__shfl((int)base, leader, 64);
      if (eq) {
        const int rank = __builtin_popcountll(me & ((1ull << lane) - 1ull));
        const unsigned pos = base + (unsigned)rank;
        if (pos < (unsigned)EQCAP) eqBuf[b * EQCAP + pos] = (unsigned)i;
      }
    }
  }
}

// resolve ties at the exact threshold: take lowest indices
__global__ __launch_bounds__(256) void eqres_kernel(Ctrl* __restrict__ ctrl, const unsigned* __restrict__ eqBuf,
                                                    unsigned long long* __restrict__ sel) {
  __shared__ unsigned si[EQCAP];
  const int b = blockIdx.x;
  const unsigned need = ctrl[b].needEq;
  unsigned cnt = ctrl[b].eqCount; if (cnt > EQCAP) cnt = EQCAP;
  const unsigned base = ctrl[b].selCount;
  const unsigned long long thrHi = ((unsigned long long)ctrl[b].thr) << 32;
  if (cnt <= need) {
    for (unsigned e = threadIdx.x; e < cnt; e += 256)
      sel[b * KPAD + base + e] = thrHi | (unsigned long long)eqBuf[b * EQCAP + e];
    if (threadIdx.x == 0) ctrl[b].total = base + cnt;
  } else {
    for (int k = threadIdx.x; k < EQCAP; k += 256)
      si[k] = (k < (int)cnt) ? eqBuf[b * EQCAP + k] : 0xFFFFFFFFu;
    __syncthreads();
    for (int k = 2; k <= EQCAP; k <<= 1)
      for (int j = k >> 1; j > 0; j >>= 1) {
        for (int idx = threadIdx.x; idx < EQCAP; idx += 256) {
          const int p = idx ^ j;
          if (p > idx) {
            const unsigned a = si[idx], c = si[p];
            const bool up = ((idx & k) == 0);
            if ((a > c) == up) { si[idx] = c; si[p] = a; }
          }
        }
        __syncthreads();
      }
    for (unsigned e = threadIdx.x; e < need; e += 256)
      sel[b * KPAD + base + e] = thrHi | (unsigned long long)si[e];
    if (threadIdx.x == 0) ctrl[b].total = base + need;
  }
}

// full sort of the 6000 selected: key = (scorebits, 0xFFFFFFFF - idx), descending == lax.top_k order
__global__ __launch_bounds__(1024) void sort_kernel(const Ctrl* __restrict__ ctrl,
                                                    const unsigned long long* __restrict__ sel,
                                                    unsigned* __restrict__ sidx) {
  __shared__ unsigned long long skey[8192];  // 64 KiB
  const int b = blockIdx.x;
  int total = (int)ctrl[b].total; if (total > KSEL) total = KSEL;
  for (int i = threadIdx.x; i < 8192; i += 1024) {
    unsigned long long kp = ~0ull;
    if (i < total) {
      const unsigned long long e = sel[b * KPAD + i];
      const unsigned bits = (unsigned)(e >> 32);
      const unsigned idx = (unsigned)e;
      const unsigned long long key = ((unsigned long long)bits << 32) | (unsigned long long)(0xFFFFFFFFu - idx);
      kp = ~key;  // sort ascending on ~key == descending on key
    }
    skey[i] = kp;
  }
  __syncthreads();
  for (int k = 2; k <= 8192; k <<= 1)
    for (int j = k >> 1; j > 0; j >>= 1) {
      for (int i = threadIdx.x; i < 8192; i += 1024) {
        const int p = i ^ j;
        if (p > i) {
          const unsigned long long a = skey[i], c = skey[p];
          const bool up = ((i & k) == 0);
          if ((a > c) == up) { skey[i] = c; skey[p] = a; }
        }
      }
      __syncthreads();
    }
  for (int r = threadIdx.x; r < KSEL; r += 1024) {
    const unsigned long long key = ~skey[r];
    sidx[b * KPAD + r] = 0xFFFFFFFFu - (unsigned)(key & 0xFFFFFFFFull);
  }
}

__global__ __launch_bounds__(256) void decode_kernel(const float* __restrict__ anchors,
                                                     const float* __restrict__ bbox,
                                                     const unsigned* __restrict__ sidx,
                                                     float4* __restrict__ boxes, int N) {
  const int b = blockIdx.y;
  const int j = blockIdx.x * 256 + (int)threadIdx.x;
  if (j >= KSEL) return;
  unsigned idx = sidx[b * KPAD + j];
  if (idx >= (unsigned)N) idx = 0;  // safety
  const float4 A = ((const float4*)anchors)[(size_t)b * N + idx];
  const float4 R = ((const float4*)bbox)[(size_t)b * N + idx];
  // exact f32 replication of reference (contract(off) is file-scope)
  const float d0 = R.x * 0.1f, d1 = R.y * 0.1f, d2 = R.z * 0.2f, d3 = R.w * 0.2f;
  const float h = A.z - A.x;
  const float w = A.w - A.y;
  const float cy = A.x + 0.5f * h + d0 * h;
  const float cx = A.y + 0.5f * w + d1 * w;
  const float e2 = (float)exp((double)d2);  // correctly-rounded f32 exp
  const float e3 = (float)exp((double)d3);
  const float h2 = h * e2;
  const float w2 = w * e3;
  float y1 = cy - 0.5f * h2;
  float x1 = cx - 0.5f * w2;
  float y2 = y1 + h2;
  float x2 = x1 + w2;
  y1 = fminf(fmaxf(y1, 0.0f), 1.0f);
  x1 = fminf(fmaxf(x1, 0.0f), 1.0f);
  y2 = fminf(fmaxf(y2, 0.0f), 1.0f);
  x2 = fminf(fmaxf(x2, 0.0f), 1.0f);
  boxes[b * KPAD + j] = make_float4(y1, x1, y2, x2);
}

// exact greedy NMS via sliding-window batched selection.
// One block per image. Per round: gather next <=64 alive indices; wave 0 resolves
// the window exactly (greedy replay via shfl/ballot bitmasks); all threads apply
// accepted heads' suppression to the alive tail in parallel.
__global__ __launch_bounds__(1024) void nms_kernel(const float4* __restrict__ boxes, float* __restrict__ out) {
  const int b = blockIdx.x;
  const int tid = threadIdx.x;
  const int lane = tid & 63;
  const float4* gbox = boxes + b * KPAD;
  float* outB = out + b * (PROP * 4);

  __shared__ unsigned long long smask[94];   // alive bitmask over 6016 slots
  __shared__ int s_widx[64];
  __shared__ float4 s_wbox[64];
  __shared__ float s_wha[64];
  __shared__ int s_cnt, s_nAcc, s_total, s_cursor;

  for (int k = tid; k < 94; k += 1024)
    smask[k] = (k == 93) ? ((1ull << 48) - 1ull) : ~0ull;  // bits 0..5999 alive
  if (tid == 0) { s_cursor = 0; s_total = 0; }
  __syncthreads();

  // M = 0.7f + 2^-25: round(inter/denom) > 0.7f  <=>  inter >= M*denom (exact in double)
  const double M = 0.7000000178813934326171875;

  for (int round = 0; round < PROP; ++round) {
    // ---- gather next <=64 alive indices ----
    if (tid == 0) {
      int cnt = 0;
      const int cur = s_cursor;
      int w = cur >> 6;
      unsigned long long word = (w < 94) ? (smask[w] & (~0ull << (cur & 63))) : 0ull;
      while (cnt < 64) {
        while (word == 0ull && ++w < 94) word = smask[w];
        if (w >= 94) break;
        const int bit = __builtin_ctzll(word);
        word &= word - 1ull;
        s_widx[cnt++] = (w << 6) | bit;
      }
      s_cnt = cnt;
      s_cursor = cnt ? (s_widx[cnt - 1] + 1) : KSEL;
    }
    __syncthreads();  // B1
    const int cnt = s_cnt;
    const int tailStart = s_cursor;
    if (cnt == 0) break;

    // ---- window resolution: wave 0, exact greedy replay ----
    if (tid < 64) {
      const int j = (lane < cnt) ? s_widx[lane] : -1;
      float4 v = make_float4(0.f, 0.f, 0.f, 0.f);
      if (j >= 0) v = gbox[j];
      const float a = (v.z - v.x) * (v.w - v.y);
      const int totalOld = s_total;
      unsigned long long aliveW = __ballot(j >= 0);
      unsigned long long acc = 0ull;
      for (int i = 0; i < 64; ++i) {
        const float hx = __shfl(v.x, i), hy = __shfl(v.y, i);
        const float hz = __shfl(v.z, i), hw = __shfl(v.w, i);
        const float ha = __shfl(a, i);
        bool s = false;
        if (j >= 0 && lane > i) {
          const float iy1 = fmaxf(hx, v.x);
          const float ix1 = fmaxf(hy, v.y);
          const float iy2 = fminf(hz, v.z);
          const float ix2 = fminf(hw, v.w);
          const float dy = fmaxf(iy2 - iy1, 0.0f);
          const float dx = fmaxf(ix2 - ix1, 0.0f);
          const float inter = dy * dx;
          const float denom = ha + a - inter + 1e-12f;
          s = ((double)inter >= M * (double)denom);
        }
        const unsigned long long m = __ballot(s);
        if (aliveW & (1ull << i)) { acc |= 1ull << i; aliveW &= ~m; }
      }
      // truncate to the remaining selection budget (keep lowest bits = earliest)
      const int need = PROP - totalOld;
      int na = __popcll(acc);
      if (na > need) {
        unsigned long long t = acc, a2 = 0ull;
        for (int c = 0; c < need; ++c) { a2 |= t & (0ull - t); t &= t - 1ull; }
        acc = a2; na = need;
      }
      if ((acc >> lane) & 1ull) {
        const int r = __popcll(acc & ((1ull << lane) - 1ull));
        float* o = outB + (size_t)(totalOld + r) * 4;
        o[0] = v.x; o[1] = v.y; o[2] = v.z; o[3] = v.w;
        s_wbox[r] = v; s_wha[r] = a;
      }
      if (lane == 0) { s_nAcc = na; s_total = totalOld + na; }
      // all window boxes are now resolved (selected or suppressed): remove from alive set
      if (j >= 0) atomicAnd(&smask[j >> 6], ~(1ull << (j & 63)));
    }
    __syncthreads();  // B2
    const int total = s_total;
    const int nAcc = s_nAcc;
    if (total >= PROP) break;

    // ---- tail suppression: all threads, parallel over alive tail boxes ----
    for (int j = tailStart + tid; j < KSEL; j += 1024) {
      if (!((smask[j >> 6] >> (j & 63)) & 1ull)) continue;
      const float4 v = gbox[j];
      const float a = (v.z - v.x) * (v.w - v.y);
      bool supp = false;
      for (int r = 0; r < nAcc; ++r) {
        const float4 hb = s_wbox[r];
        const float ha = s_wha[r];
        const float iy1 = fmaxf(hb.x, v.x);
        const float ix1 = fmaxf(hb.y, v.y);
        const float iy2 = fminf(hb.z, v.z);
        const float ix2 = fminf(hb.w, v.w);
        const float dy = fmaxf(iy2 - iy1, 0.0f);
        const float dx = fmaxf(ix2 - ix1, 0.0f);
        const float inter = dy * dx;
        const float denom = ha + a - inter + 1e-12f;
        if ((double)inter >= M * (double)denom) { supp = true; break; }
      }
      if (supp) atomicAnd(&smask[j >> 6], ~(1ull << (j & 63)));
    }
    __syncthreads();  // B3: mask stable before next gather
  }

  // zero-pad the remainder (matches reference valid=False padding)
  const int written = s_total;
  for (int u = written * 4 + tid; u < PROP * 4; u += 1024) outB[u] = 0.0f;
}

extern "C" void kernel_launch(void* const* d_in, const int* in_sizes, int n_in,
                              void* d_out, int out_size, void* d_ws, size_t ws_size,
                              hipStream_t stream) {
  (void)n_in; (void)out_size; (void)ws_size;
  const float* probs = (const float*)d_in[0];
  const float* bbox = (const float*)d_in[1];
  const float* anchors = (const float*)d_in[2];
  float* out = (float*)d_out;
  char* ws = (char*)d_ws;
  const int N = in_sizes[0] / (NB * 2);  // 261888

  unsigned* hist1 = (unsigned*)(ws + OFF_HIST1);
  unsigned* hist2 = (unsigned*)(ws + OFF_HIST2);
  unsigned* hist3 = (unsigned*)(ws + OFF_HIST3);
  Ctrl* ctrl = (Ctrl*)(ws + OFF_CTRL);
  unsigned long long* sel = (unsigned long long*)(ws + OFF_SEL);
  unsigned* eqBuf = (unsigned*)(ws + OFF_EQ);
  unsigned* sidx = (unsigned*)(ws + OFF_SIDX);
  float4* boxes = (float4*)(ws + OFF_BOX);

  const int zeroN = (int)(OFF_SEL / 4);  // hist1+hist2+hist3+ctrl
  zero_kernel<<<dim3((zeroN + 255) / 256), dim3(256), 0, stream>>>((unsigned*)ws, zeroN);

  const int gx = (N + 16383) / 16384;
  hist_kernel<<<dim3(gx, NB), dim3(256), 0, stream>>>(1, probs, hist1, ctrl, N);
  scan_kernel<<<dim3(NB), dim3(64), 0, stream>>>(1, hist1, ctrl);
  hist_kernel<<<dim3(gx, NB), dim3(256), 0, stream>>>(2, probs, hist2, ctrl, N);
  scan_kernel<<<dim3(NB), dim3(64), 0, stream>>>(2, hist2, ctrl);
  hist_kernel<<<dim3(gx, NB), dim3(256), 0, stream>>>(3, probs, hist3, ctrl, N);
  scan_kernel<<<dim3(NB), dim3(64), 0, stream>>>(3, hist3, ctrl);
  compact_kernel<<<dim3(gx, NB), dim3(256), 0, stream>>>(probs, ctrl, sel, eqBuf, N);
  eqres_kernel<<<dim3(NB), dim3(256), 0, stream>>>(ctrl, eqBuf, sel);
  sort_kernel<<<dim3(NB), dim3(1024), 0, stream>>>(ctrl, sel, sidx);
  decode_kernel<<<dim3((KSEL + 255) / 256, NB), dim3(256), 0, stream>>>(anchors, bbox, sidx, boxes, N);
  nms_kernel<<<dim3(NB), dim3(1024), 0, stream>>>(boxes, out);
}

// Round 3
// 879.277 us; speedup vs baseline: 1.9790x; 1.6976x over previous
//
#include <hip/hip_runtime.h>

#pragma clang fp contract(off)

#define NB 8
#define KSEL 6000
#define KPAD 6016
#define PROP 1000
#define EQCAP 8192
#define NWORDS 94
#define NTILE 94

// ws layout (bytes)
#define OFF_HIST1 0u          // 8*4096*4 = 131072
#define OFF_HIST2 131072u     // 8*4096*4
#define OFF_HIST3 262144u     // 8*256*4 = 8192
#define OFF_CTRL  270336u     // 8*64 = 512
#define OFF_SEL   270848u     // 8*6016*8 = 385024
#define OFF_EQ    655872u     // 8*8192*4 = 262144
#define OFF_SIDX  918016u     // 8*6016*4 = 192512
#define OFF_BOX   1110528u    // 8*6016*16 = 770048 -> end 1880576
#define OFF_MAT   1884160u    // 8*94*6016*8 = 36192256 -> end 38076416
#define MAT_BYTES 36192256ull

struct Ctrl {
  unsigned t1, rem1, t2, rem2, thr, needEq, selCount, eqCount, total;
  unsigned pad[7];
};

__global__ __launch_bounds__(256) void zero_kernel(unsigned* p, int n) {
  int i = blockIdx.x * 256 + threadIdx.x;
  if (i < n) p[i] = 0u;
}

// phase 1: bin = bits>>20 (4096 bins); phase 2: mid 12 bits within t1; phase 3: low 8 bits within (t1,t2)
__global__ __launch_bounds__(256) void hist_kernel(int phase, const float* __restrict__ probs,
                                                   unsigned* __restrict__ hist,
                                                   const Ctrl* __restrict__ ctrl, int N) {
  __shared__ unsigned lh[4096];
  const int b = blockIdx.y;
  const int nb = (phase == 3) ? 256 : 4096;
  for (int k = threadIdx.x; k < nb; k += 256) lh[k] = 0u;
  unsigned t1 = 0, pre24 = 0;
  if (phase == 2) t1 = ctrl[b].t1;
  if (phase == 3) pre24 = (ctrl[b].t1 << 12) | ctrl[b].t2;
  __syncthreads();
  const int start = blockIdx.x * 16384;
  const int end = min(start + 16384, N);
  for (int i = start + (int)threadIdx.x; i < end; i += 256) {
    const unsigned bits = __float_as_uint(probs[(size_t)(b * N + i) * 2 + 1]);
    if (phase == 1) atomicAdd(&lh[bits >> 20], 1u);
    else if (phase == 2) { if ((bits >> 20) == t1) atomicAdd(&lh[(bits >> 8) & 0xFFFu], 1u); }
    else { if ((bits >> 8) == pre24) atomicAdd(&lh[bits & 0xFFu], 1u); }
  }
  __syncthreads();
  for (int k = threadIdx.x; k < nb; k += 256) {
    const unsigned v = lh[k];
    if (v) atomicAdd(&hist[b * nb + k], v);
  }
}

// one wave per image: descending cumulative scan, find threshold bin
__global__ __launch_bounds__(64) void scan_kernel(int phase, const unsigned* __restrict__ hist,
                                                  Ctrl* __restrict__ ctrl) {
  const int b = blockIdx.x;
  const int lane = threadIdx.x;
  const int nb = (phase == 3) ? 256 : 4096;
  const int chunks = nb >> 6;
  const unsigned target = (phase == 1) ? 6000u : ((phase == 2) ? ctrl[b].rem1 : ctrl[b].rem2);
  const unsigned* h = hist + b * nb;
  const int topbin = nb - 1 - lane * chunks;
  unsigned mysum = 0;
  for (int c = 0; c < chunks; c++) mysum += h[topbin - c];
  unsigned cum = mysum;
  for (int off = 1; off < 64; off <<= 1) {
    const unsigned v = __shfl_up(cum, off, 64);
    if (lane >= off) cum += v;
  }
  const unsigned prev = cum - mysum;
  if (prev < target && cum >= target) {
    unsigned c2 = prev;
    for (int c = 0; c < chunks; c++) {
      const int bin = topbin - c;
      const unsigned hv = h[bin];
      if (c2 + hv >= target) {
        const unsigned rem = target - c2;
        if (phase == 1) { ctrl[b].t1 = (unsigned)bin; ctrl[b].rem1 = rem; }
        else if (phase == 2) { ctrl[b].t2 = (unsigned)bin; ctrl[b].rem2 = rem; }
        else {
          ctrl[b].thr = (ctrl[b].t1 << 20) | (ctrl[b].t2 << 8) | (unsigned)bin;
          ctrl[b].needEq = rem;
        }
        break;
      }
      c2 += hv;
    }
  }
}

__global__ __launch_bounds__(256) void compact_kernel(const float* __restrict__ probs, Ctrl* __restrict__ ctrl,
                                                      unsigned long long* __restrict__ sel,
                                                      unsigned* __restrict__ eqBuf, int N) {
  const int b = blockIdx.y;
  const unsigned THR = ctrl[b].thr;
  const int start = blockIdx.x * 16384;
  const int end = min(start + 16384, N);
  const int lane = threadIdx.x & 63;
  const int iters = (end - start + 255) / 256;
  for (int it = 0; it < iters; it++) {
    const int i = start + it * 256 + (int)threadIdx.x;
    const bool v = i < end;
    unsigned bits = 0u;
    if (v) bits = __float_as_uint(probs[(size_t)(b * N + i) * 2 + 1]);
    const bool gt = v && (bits > THR);
    const bool eq = v && (bits == THR);
    const unsigned long long mg = __ballot(gt);
    if (mg) {
      const int leader = __builtin_ctzll(mg);
      unsigned base = 0;
      if (lane == leader) base = atomicAdd(&ctrl[b].selCount, (unsigned)__builtin_popcountll(mg));
      base = (unsigned)__shfl((int)base, leader, 64);
      if (gt) {
        const int rank = __builtin_popcountll(mg & ((1ull << lane) - 1ull));
        const unsigned pos = base + (unsigned)rank;
        if (pos < (unsigned)KPAD) sel[b * KPAD + pos] = ((unsigned long long)bits << 32) | (unsigned)i;
      }
    }
    const unsigned long long me = __ballot(eq);
    if (me) {
      const int leader = __builtin_ctzll(me);
      unsigned base = 0;
      if (lane == leader) base = atomicAdd(&ctrl[b].eqCount, (unsigned)__builtin_popcountll(me));
      base = (unsigned)__shfl((int)base, leader, 64);
      if (eq) {
        const int rank = __builtin_popcountll(me & ((1ull << lane) - 1ull));
        const unsigned pos = base + (unsigned)rank;
        if (pos < (unsigned)EQCAP) eqBuf[b * EQCAP + pos] = (unsigned)i;
      }
    }
  }
}

// resolve ties at the exact threshold: take lowest indices
__global__ __launch_bounds__(256) void eqres_kernel(Ctrl* __restrict__ ctrl, const unsigned* __restrict__ eqBuf,
                                                    unsigned long long* __restrict__ sel) {
  __shared__ unsigned si[EQCAP];
  const int b = blockIdx.x;
  const unsigned need = ctrl[b].needEq;
  unsigned cnt = ctrl[b].eqCount; if (cnt > EQCAP) cnt = EQCAP;
  const unsigned base = ctrl[b].selCount;
  const unsigned long long thrHi = ((unsigned long long)ctrl[b].thr) << 32;
  if (cnt <= need) {
    for (unsigned e = threadIdx.x; e < cnt; e += 256)
      sel[b * KPAD + base + e] = thrHi | (unsigned long long)eqBuf[b * EQCAP + e];
    if (threadIdx.x == 0) ctrl[b].total = base + cnt;
  } else {
    for (int k = threadIdx.x; k < EQCAP; k += 256)
      si[k] = (k < (int)cnt) ? eqBuf[b * EQCAP + k] : 0xFFFFFFFFu;
    __syncthreads();
    for (int k = 2; k <= EQCAP; k <<= 1)
      for (int j = k >> 1; j > 0; j >>= 1) {
        for (int idx = threadIdx.x; idx < EQCAP; idx += 256) {
          const int p = idx ^ j;
          if (p > idx) {
            const unsigned a = si[idx], c = si[p];
            const bool up = ((idx & k) == 0);
            if ((a > c) == up) { si[idx] = c; si[p] = a; }
          }
        }
        __syncthreads();
      }
    for (unsigned e = threadIdx.x; e < need; e += 256)
      sel[b * KPAD + base + e] = thrHi | (unsigned long long)si[e];
    if (threadIdx.x == 0) ctrl[b].total = base + need;
  }
}

// full sort of the 6000 selected: key = (scorebits, 0xFFFFFFFF - idx), descending == lax.top_k order
__global__ __launch_bounds__(1024) void sort_kernel(const Ctrl* __restrict__ ctrl,
                                                    const unsigned long long* __restrict__ sel,
                                                    unsigned* __restrict__ sidx) {
  __shared__ unsigned long long skey[8192];  // 64 KiB
  const int b = blockIdx.x;
  int total = (int)ctrl[b].total; if (total > KSEL) total = KSEL;
  for (int i = threadIdx.x; i < 8192; i += 1024) {
    unsigned long long kp = ~0ull;
    if (i < total) {
      const unsigned long long e = sel[b * KPAD + i];
      const unsigned bits = (unsigned)(e >> 32);
      const unsigned idx = (unsigned)e;
      const unsigned long long key = ((unsigned long long)bits << 32) | (unsigned long long)(0xFFFFFFFFu - idx);
      kp = ~key;  // sort ascending on ~key == descending on key
    }
    skey[i] = kp;
  }
  __syncthreads();
  for (int k = 2; k <= 8192; k <<= 1)
    for (int j = k >> 1; j > 0; j >>= 1) {
      for (int i = threadIdx.x; i < 8192; i += 1024) {
        const int p = i ^ j;
        if (p > i) {
          const unsigned long long a = skey[i], c = skey[p];
          const bool up = ((i & k) == 0);
          if ((a > c) == up) { skey[i] = c; skey[p] = a; }
        }
      }
      __syncthreads();
    }
  for (int r = threadIdx.x; r < KSEL; r += 1024) {
    const unsigned long long key = ~skey[r];
    sidx[b * KPAD + r] = 0xFFFFFFFFu - (unsigned)(key & 0xFFFFFFFFull);
  }
}

__global__ __launch_bounds__(256) void decode_kernel(const float* __restrict__ anchors,
                                                     const float* __restrict__ bbox,
                                                     const unsigned* __restrict__ sidx,
                                                     float4* __restrict__ boxes, int N) {
  const int b = blockIdx.y;
  const int j = blockIdx.x * 256 + (int)threadIdx.x;
  if (j >= KSEL) return;
  unsigned idx = sidx[b * KPAD + j];
  if (idx >= (unsigned)N) idx = 0;  // safety
  const float4 A = ((const float4*)anchors)[(size_t)b * N + idx];
  const float4 R = ((const float4*)bbox)[(size_t)b * N + idx];
  // exact f32 replication of reference (contract(off) is file-scope)
  const float d0 = R.x * 0.1f, d1 = R.y * 0.1f, d2 = R.z * 0.2f, d3 = R.w * 0.2f;
  const float h = A.z - A.x;
  const float w = A.w - A.y;
  const float cy = A.x + 0.5f * h + d0 * h;
  const float cx = A.y + 0.5f * w + d1 * w;
  const float e2 = (float)exp((double)d2);  // correctly-rounded f32 exp
  const float e3 = (float)exp((double)d3);
  const float h2 = h * e2;
  const float w2 = w * e3;
  float y1 = cy - 0.5f * h2;
  float x1 = cx - 0.5f * w2;
  float y2 = y1 + h2;
  float x2 = x1 + w2;
  y1 = fminf(fmaxf(y1, 0.0f), 1.0f);
  x1 = fminf(fmaxf(x1, 0.0f), 1.0f);
  y2 = fminf(fmaxf(y2, 0.0f), 1.0f);
  x2 = fminf(fmaxf(x2, 0.0f), 1.0f);
  boxes[b * KPAD + j] = make_float4(y1, x1, y2, x2);
}

// ---- bitmatrix NMS path ----
// suppmat: upper-triangular suppression matrix. Storage: mat[(b*94 + jword)*KPAD + i]
// = 64-bit word of columns [jword*64, jword*64+64) for row i. Only jword >= i/64 written.
__global__ __launch_bounds__(256) void suppmat_kernel(const float4* __restrict__ boxes,
                                                      unsigned long long* __restrict__ mat) {
  const int b = blockIdx.y;
  int t = blockIdx.x;
  int it = 0, rem = NTILE;
  while (t >= rem) { t -= rem; ++it; rem = NTILE - it; }
  const int jt = it + t;
  const int wave = threadIdx.x >> 6;
  const int lane = threadIdx.x & 63;
  const float4* gbox = boxes + b * KPAD;
  __shared__ float4 srow[64];
  __shared__ float sarea[64];
  if (threadIdx.x < 64) {
    const float4 v = gbox[it * 64 + threadIdx.x];
    srow[threadIdx.x] = v;
    sarea[threadIdx.x] = (v.z - v.x) * (v.w - v.y);
  }
  const int c = jt * 64 + lane;  // column index
  const float4 cv = gbox[c];
  const float ca = (cv.z - cv.x) * (cv.w - cv.y);
  __syncthreads();
  const double M = 0.7000000178813934326171875;
  unsigned long long* ocol = mat + ((size_t)b * NWORDS + jt) * KPAD;
  for (int r = wave; r < 64; r += 4) {
    const int i = it * 64 + r;
    const float4 hb = srow[r];
    const float ha = sarea[r];
    const float iy1 = fmaxf(hb.x, cv.x);
    const float ix1 = fmaxf(hb.y, cv.y);
    const float iy2 = fminf(hb.z, cv.z);
    const float ix2 = fminf(hb.w, cv.w);
    const float dy = fmaxf(iy2 - iy1, 0.0f);
    const float dx = fmaxf(ix2 - ix1, 0.0f);
    const float inter = dy * dx;
    const float denom = ha + ca - inter + 1e-12f;
    const bool s = (c > i) && ((double)inter >= M * (double)denom);
    const unsigned long long w = __ballot(s);
    if (lane == 0) ocol[i] = w;
  }
}

// one wave per image: exact greedy replay over the bitmatrix
__global__ __launch_bounds__(64) void resolve_kernel(const Ctrl* __restrict__ ctrl,
                                                     const float4* __restrict__ boxes,
                                                     const unsigned long long* __restrict__ mat,
                                                     float* __restrict__ out) {
  const int b = blockIdx.x;
  const int lane = threadIdx.x;
  int total = (int)ctrl[b].total; if (total > KSEL) total = KSEL;
  // alive words: lane owns word `lane` and word `64+lane` (lanes 0..29)
  unsigned long long a0, a1;
  {
    const int lo0 = lane * 64;
    a0 = (lo0 >= total) ? 0ull : ((total - lo0 >= 64) ? ~0ull : ((1ull << (total - lo0)) - 1ull));
    const int w1 = 64 + lane;
    if (w1 < NWORDS) {
      const int lo1 = w1 * 64;
      a1 = (lo1 >= total) ? 0ull : ((total - lo1 >= 64) ? ~0ull : ((1ull << (total - lo1)) - 1ull));
    } else a1 = 0ull;
  }
  __shared__ int s_sel[PROP];
  const unsigned long long* cmat = mat + (size_t)b * NWORDS * KPAD;
  int nsel = 0;
  while (nsel < PROP) {
    // find lowest alive index
    int p = a0 ? (lane * 64 + __builtin_ctzll(a0)) : 0x7FFFFFFF;
    if (a1) p = min(p, (64 + lane) * 64 + __builtin_ctzll(a1));
    for (int off = 32; off >= 1; off >>= 1) p = min(p, __shfl_xor(p, off, 64));
    if (p >= total) break;
    if (lane == 0) s_sel[nsel] = p;
    nsel++;
    // clear bits <= p (resolved region), then AND out row p's suppression words
    const int pw = p >> 6, pb = p & 63;
    if (lane < pw) a0 = 0ull;
    else if (lane == pw) a0 &= ~(((1ull << pb) << 1) - 1ull);
    if (64 + lane < pw) a1 = 0ull;
    else if (64 + lane == pw) a1 &= ~(((1ull << pb) << 1) - 1ull);
    a0 &= ~cmat[(size_t)lane * KPAD + p];          // words < pw: a0 already 0, garbage harmless
    if (64 + lane < NWORDS) a1 &= ~cmat[(size_t)(64 + lane) * KPAD + p];
  }
  __syncthreads();
  float4* outv = (float4*)(out + (size_t)b * PROP * 4);
  const float4* gbox = boxes + b * KPAD;
  for (int k = lane; k < PROP; k += 64)
    outv[k] = (k < nsel) ? gbox[s_sel[k]] : make_float4(0.f, 0.f, 0.f, 0.f);
}

// ---- fallback windowed NMS (round-2, known-passing) for small ws ----
__global__ __launch_bounds__(1024) void nms_kernel(const float4* __restrict__ boxes, float* __restrict__ out) {
  const int b = blockIdx.x;
  const int tid = threadIdx.x;
  const int lane = tid & 63;
  const float4* gbox = boxes + b * KPAD;
  float* outB = out + b * (PROP * 4);
  __shared__ unsigned long long smask[94];
  __shared__ int s_widx[64];
  __shared__ float4 s_wbox[64];
  __shared__ float s_wha[64];
  __shared__ int s_cnt, s_nAcc, s_total, s_cursor;
  for (int k = tid; k < 94; k += 1024)
    smask[k] = (k == 93) ? ((1ull << 48) - 1ull) : ~0ull;
  if (tid == 0) { s_cursor = 0; s_total = 0; }
  __syncthreads();
  const double M = 0.7000000178813934326171875;
  for (int round = 0; round < PROP; ++round) {
    if (tid == 0) {
      int cnt = 0;
      const int cur = s_cursor;
      int w = cur >> 6;
      unsigned long long word = (w < 94) ? (smask[w] & (~0ull << (cur & 63))) : 0ull;
      while (cnt < 64) {
        while (word == 0ull && ++w < 94) word = smask[w];
        if (w >= 94) break;
        const int bit = __builtin_ctzll(word);
        word &= word - 1ull;
        s_widx[cnt++] = (w << 6) | bit;
      }
      s_cnt = cnt;
      s_cursor = cnt ? (s_widx[cnt - 1] + 1) : KSEL;
    }
    __syncthreads();
    const int cnt = s_cnt;
    const int tailStart = s_cursor;
    if (cnt == 0) break;
    if (tid < 64) {
      const int j = (lane < cnt) ? s_widx[lane] : -1;
      float4 v = make_float4(0.f, 0.f, 0.f, 0.f);
      if (j >= 0) v = gbox[j];
      const float a = (v.z - v.x) * (v.w - v.y);
      const int totalOld = s_total;
      unsigned long long aliveW = __ballot(j >= 0);
      unsigned long long acc = 0ull;
      for (int i = 0; i < 64; ++i) {
        const float hx = __shfl(v.x, i), hy = __shfl(v.y, i);
        const float hz = __shfl(v.z, i), hw = __shfl(v.w, i);
        const float ha = __shfl(a, i);
        bool s = false;
        if (j >= 0 && lane > i) {
          const float iy1 = fmaxf(hx, v.x);
          const float ix1 = fmaxf(hy, v.y);
          const float iy2 = fminf(hz, v.z);
          const float ix2 = fminf(hw, v.w);
          const float dy = fmaxf(iy2 - iy1, 0.0f);
          const float dx = fmaxf(ix2 - ix1, 0.0f);
          const float inter = dy * dx;
          const float denom = ha + a - inter + 1e-12f;
          s = ((double)inter >= M * (double)denom);
        }
        const unsigned long long m = __ballot(s);
        if (aliveW & (1ull << i)) { acc |= 1ull << i; aliveW &= ~m; }
      }
      const int need = PROP - totalOld;
      int na = __popcll(acc);
      if (na > need) {
        unsigned long long t = acc, a2 = 0ull;
        for (int c2 = 0; c2 < need; ++c2) { a2 |= t & (0ull - t); t &= t - 1ull; }
        acc = a2; na = need;
      }
      if ((acc >> lane) & 1ull) {
        const int r = __popcll(acc & ((1ull << lane) - 1ull));
        float* o = outB + (size_t)(totalOld + r) * 4;
        o[0] = v.x; o[1] = v.y; o[2] = v.z; o[3] = v.w;
        s_wbox[r] = v; s_wha[r] = a;
      }
      if (lane == 0) { s_nAcc = na; s_total = totalOld + na; }
      if (j >= 0) atomicAnd(&smask[j >> 6], ~(1ull << (j & 63)));
    }
    __syncthreads();
    const int total = s_total;
    const int nAcc = s_nAcc;
    if (total >= PROP) break;
    for (int j = tailStart + tid; j < KSEL; j += 1024) {
      if (!((smask[j >> 6] >> (j & 63)) & 1ull)) continue;
      const float4 v = gbox[j];
      const float a = (v.z - v.x) * (v.w - v.y);
      bool supp = false;
      for (int r = 0; r < nAcc; ++r) {
        const float4 hb = s_wbox[r];
        const float ha = s_wha[r];
        const float iy1 = fmaxf(hb.x, v.x);
        const float ix1 = fmaxf(hb.y, v.y);
        const float iy2 = fminf(hb.z, v.z);
        const float ix2 = fminf(hb.w, v.w);
        const float dy = fmaxf(iy2 - iy1, 0.0f);
        const float dx = fmaxf(ix2 - ix1, 0.0f);
        const float inter = dy * dx;
        const float denom = ha + a - inter + 1e-12f;
        if ((double)inter >= M * (double)denom) { supp = true; break; }
      }
      if (supp) atomicAnd(&smask[j >> 6], ~(1ull << (j & 63)));
    }
    __syncthreads();
  }
  const int written = s_total;
  for (int u = written * 4 + tid; u < PROP * 4; u += 1024) outB[u] = 0.0f;
}

extern "C" void kernel_launch(void* const* d_in, const int* in_sizes, int n_in,
                              void* d_out, int out_size, void* d_ws, size_t ws_size,
                              hipStream_t stream) {
  (void)n_in; (void)out_size;
  const float* probs = (const float*)d_in[0];
  const float* bbox = (const float*)d_in[1];
  const float* anchors = (const float*)d_in[2];
  float* out = (float*)d_out;
  char* ws = (char*)d_ws;
  const int N = in_sizes[0] / (NB * 2);  // 261888

  unsigned* hist1 = (unsigned*)(ws + OFF_HIST1);
  unsigned* hist2 = (unsigned*)(ws + OFF_HIST2);
  unsigned* hist3 = (unsigned*)(ws + OFF_HIST3);
  Ctrl* ctrl = (Ctrl*)(ws + OFF_CTRL);
  unsigned long long* sel = (unsigned long long*)(ws + OFF_SEL);
  unsigned* eqBuf = (unsigned*)(ws + OFF_EQ);
  unsigned* sidx = (unsigned*)(ws + OFF_SIDX);
  float4* boxes = (float4*)(ws + OFF_BOX);
  unsigned long long* mat = (unsigned long long*)(ws + OFF_MAT);

  const int zeroN = (int)(OFF_SEL / 4);  // hist1+hist2+hist3+ctrl
  zero_kernel<<<dim3((zeroN + 255) / 256), dim3(256), 0, stream>>>((unsigned*)ws, zeroN);

  const int gx = (N + 16383) / 16384;
  hist_kernel<<<dim3(gx, NB), dim3(256), 0, stream>>>(1, probs, hist1, ctrl, N);
  scan_kernel<<<dim3(NB), dim3(64), 0, stream>>>(1, hist1, ctrl);
  hist_kernel<<<dim3(gx, NB), dim3(256), 0, stream>>>(2, probs, hist2, ctrl, N);
  scan_kernel<<<dim3(NB), dim3(64), 0, stream>>>(2, hist2, ctrl);
  hist_kernel<<<dim3(gx, NB), dim3(256), 0, stream>>>(3, probs, hist3, ctrl, N);
  scan_kernel<<<dim3(NB), dim3(64), 0, stream>>>(3, hist3, ctrl);
  compact_kernel<<<dim3(gx, NB), dim3(256), 0, stream>>>(probs, ctrl, sel, eqBuf, N);
  eqres_kernel<<<dim3(NB), dim3(256), 0, stream>>>(ctrl, eqBuf, sel);
  sort_kernel<<<dim3(NB), dim3(1024), 0, stream>>>(ctrl, sel, sidx);
  decode_kernel<<<dim3((KSEL + 255) / 256, NB), dim3(256), 0, stream>>>(anchors, bbox, sidx, boxes, N);

  if (ws_size >= (size_t)OFF_MAT + MAT_BYTES) {
    suppmat_kernel<<<dim3(NTILE * (NTILE + 1) / 2, NB), dim3(256), 0, stream>>>(boxes, mat);
    resolve_kernel<<<dim3(NB), dim3(64), 0, stream>>>(ctrl, boxes, mat, out);
  } else {
    nms_kernel<<<dim3(NB), dim3(1024), 0, stream>>>(boxes, out);
  }
}

// Round 4
// 747.767 us; speedup vs baseline: 2.3271x; 1.1759x over previous
//
#include <hip/hip_runtime.h>

#pragma clang fp contract(off)

#define NB 8
#define KSEL 6000
#define KPAD 6016
#define PROP 1000
#define EQCAP 8192
#define NWORDS 94
#define NTILE 94

// ws layout (bytes)
#define OFF_HIST1 0u          // 8*4096*4 = 131072
#define OFF_HIST2 131072u     // 8*4096*4
#define OFF_HIST3 262144u     // 8*256*4 = 8192
#define OFF_CTRL  270336u     // 8*64 = 512
#define OFF_SEL   270848u     // 8*6016*8 = 385024
#define OFF_EQ    655872u     // 8*8192*4 = 262144
#define OFF_SIDX  918016u     // 8*6016*4 = 192512
#define OFF_BOX   1110528u    // 8*6016*16 = 770048 -> end 1880576
#define OFF_MAT   1884160u    // 8*6016*94*8 = 36192256 -> end 38076416
#define MAT_BYTES 36192256ull

struct Ctrl {
  unsigned t1, rem1, t2, rem2, thr, needEq, selCount, eqCount, total;
  unsigned pad[7];
};

__global__ __launch_bounds__(256) void zero_kernel(unsigned* p, int n) {
  int i = blockIdx.x * 256 + threadIdx.x;
  if (i < n) p[i] = 0u;
}

// phase 1: bin = bits>>20 (4096 bins); phase 2: mid 12 bits within t1; phase 3: low 8 bits within (t1,t2)
__global__ __launch_bounds__(256) void hist_kernel(int phase, const float* __restrict__ probs,
                                                   unsigned* __restrict__ hist,
                                                   const Ctrl* __restrict__ ctrl, int N) {
  __shared__ unsigned lh[4096];
  const int b = blockIdx.y;
  const int nb = (phase == 3) ? 256 : 4096;
  for (int k = threadIdx.x; k < nb; k += 256) lh[k] = 0u;
  unsigned t1 = 0, pre24 = 0;
  if (phase == 2) t1 = ctrl[b].t1;
  if (phase == 3) pre24 = (ctrl[b].t1 << 12) | ctrl[b].t2;
  __syncthreads();
  const int start = blockIdx.x * 16384;
  const int end = min(start + 16384, N);
  for (int i = start + (int)threadIdx.x; i < end; i += 256) {
    const unsigned bits = __float_as_uint(probs[(size_t)(b * N + i) * 2 + 1]);
    if (phase == 1) atomicAdd(&lh[bits >> 20], 1u);
    else if (phase == 2) { if ((bits >> 20) == t1) atomicAdd(&lh[(bits >> 8) & 0xFFFu], 1u); }
    else { if ((bits >> 8) == pre24) atomicAdd(&lh[bits & 0xFFu], 1u); }
  }
  __syncthreads();
  for (int k = threadIdx.x; k < nb; k += 256) {
    const unsigned v = lh[k];
    if (v) atomicAdd(&hist[b * nb + k], v);
  }
}

// one wave per image: descending cumulative scan, find threshold bin
__global__ __launch_bounds__(64) void scan_kernel(int phase, const unsigned* __restrict__ hist,
                                                  Ctrl* __restrict__ ctrl) {
  const int b = blockIdx.x;
  const int lane = threadIdx.x;
  const int nb = (phase == 3) ? 256 : 4096;
  const int chunks = nb >> 6;
  const unsigned target = (phase == 1) ? 6000u : ((phase == 2) ? ctrl[b].rem1 : ctrl[b].rem2);
  const unsigned* h = hist + b * nb;
  const int topbin = nb - 1 - lane * chunks;
  unsigned mysum = 0;
  for (int c = 0; c < chunks; c++) mysum += h[topbin - c];
  unsigned cum = mysum;
  for (int off = 1; off < 64; off <<= 1) {
    const unsigned v = __shfl_up(cum, off, 64);
    if (lane >= off) cum += v;
  }
  const unsigned prev = cum - mysum;
  if (prev < target && cum >= target) {
    unsigned c2 = prev;
    for (int c = 0; c < chunks; c++) {
      const int bin = topbin - c;
      const unsigned hv = h[bin];
      if (c2 + hv >= target) {
        const unsigned rem = target - c2;
        if (phase == 1) { ctrl[b].t1 = (unsigned)bin; ctrl[b].rem1 = rem; }
        else if (phase == 2) { ctrl[b].t2 = (unsigned)bin; ctrl[b].rem2 = rem; }
        else {
          ctrl[b].thr = (ctrl[b].t1 << 20) | (ctrl[b].t2 << 8) | (unsigned)bin;
          ctrl[b].needEq = rem;
        }
        break;
      }
      c2 += hv;
    }
  }
}

__global__ __launch_bounds__(256) void compact_kernel(const float* __restrict__ probs, Ctrl* __restrict__ ctrl,
                                                      unsigned long long* __restrict__ sel,
                                                      unsigned* __restrict__ eqBuf, int N) {
  const int b = blockIdx.y;
  const unsigned THR = ctrl[b].thr;
  const int start = blockIdx.x * 16384;
  const int end = min(start + 16384, N);
  const int lane = threadIdx.x & 63;
  const int iters = (end - start + 255) / 256;
  for (int it = 0; it < iters; it++) {
    const int i = start + it * 256 + (int)threadIdx.x;
    const bool v = i < end;
    unsigned bits = 0u;
    if (v) bits = __float_as_uint(probs[(size_t)(b * N + i) * 2 + 1]);
    const bool gt = v && (bits > THR);
    const bool eq = v && (bits == THR);
    const unsigned long long mg = __ballot(gt);
    if (mg) {
      const int leader = __builtin_ctzll(mg);
      unsigned base = 0;
      if (lane == leader) base = atomicAdd(&ctrl[b].selCount, (unsigned)__builtin_popcountll(mg));
      base = (unsigned)__shfl((int)base, leader, 64);
      if (gt) {
        const int rank = __builtin_popcountll(mg & ((1ull << lane) - 1ull));
        const unsigned pos = base + (unsigned)rank;
        if (pos < (unsigned)KPAD) sel[b * KPAD + pos] = ((unsigned long long)bits << 32) | (unsigned)i;
      }
    }
    const unsigned long long me = __ballot(eq);
    if (me) {
      const int leader = __builtin_ctzll(me);
      unsigned base = 0;
      if (lane == leader) base = atomicAdd(&ctrl[b].eqCount, (unsigned)__builtin_popcountll(me));
      base = (unsigned)__shfl((int)base, leader, 64);
      if (eq) {
        const int rank = __builtin_popcountll(me & ((1ull << lane) - 1ull));
        const unsigned pos = base + (unsigned)rank;
        if (pos < (unsigned)EQCAP) eqBuf[b * EQCAP + pos] = (unsigned)i;
      }
    }
  }
}

// resolve ties at the exact threshold: take lowest indices
__global__ __launch_bounds__(256) void eqres_kernel(Ctrl* __restrict__ ctrl, const unsigned* __restrict__ eqBuf,
                                                    unsigned long long* __restrict__ sel) {
  __shared__ unsigned si[EQCAP];
  const int b = blockIdx.x;
  const unsigned need = ctrl[b].needEq;
  unsigned cnt = ctrl[b].eqCount; if (cnt > EQCAP) cnt = EQCAP;
  const unsigned base = ctrl[b].selCount;
  const unsigned long long thrHi = ((unsigned long long)ctrl[b].thr) << 32;
  if (cnt <= need) {
    for (unsigned e = threadIdx.x; e < cnt; e += 256)
      sel[b * KPAD + base + e] = thrHi | (unsigned long long)eqBuf[b * EQCAP + e];
    if (threadIdx.x == 0) ctrl[b].total = base + cnt;
  } else {
    for (int k = threadIdx.x; k < EQCAP; k += 256)
      si[k] = (k < (int)cnt) ? eqBuf[b * EQCAP + k] : 0xFFFFFFFFu;
    __syncthreads();
    for (int k = 2; k <= EQCAP; k <<= 1)
      for (int j = k >> 1; j > 0; j >>= 1) {
        for (int idx = threadIdx.x; idx < EQCAP; idx += 256) {
          const int p = idx ^ j;
          if (p > idx) {
            const unsigned a = si[idx], c = si[p];
            const bool up = ((idx & k) == 0);
            if ((a > c) == up) { si[idx] = c; si[p] = a; }
          }
        }
        __syncthreads();
      }
    for (unsigned e = threadIdx.x; e < need; e += 256)
      sel[b * KPAD + base + e] = thrHi | (unsigned long long)si[e];
    if (threadIdx.x == 0) ctrl[b].total = base + need;
  }
}

// full sort of the 6000 selected: key = (scorebits, 0xFFFFFFFF - idx), descending == lax.top_k order
__global__ __launch_bounds__(1024) void sort_kernel(const Ctrl* __restrict__ ctrl,
                                                    const unsigned long long* __restrict__ sel,
                                                    unsigned* __restrict__ sidx) {
  __shared__ unsigned long long skey[8192];  // 64 KiB
  const int b = blockIdx.x;
  int total = (int)ctrl[b].total; if (total > KSEL) total = KSEL;
  for (int i = threadIdx.x; i < 8192; i += 1024) {
    unsigned long long kp = ~0ull;
    if (i < total) {
      const unsigned long long e = sel[b * KPAD + i];
      const unsigned bits = (unsigned)(e >> 32);
      const unsigned idx = (unsigned)e;
      const unsigned long long key = ((unsigned long long)bits << 32) | (unsigned long long)(0xFFFFFFFFu - idx);
      kp = ~key;  // sort ascending on ~key == descending on key
    }
    skey[i] = kp;
  }
  __syncthreads();
  for (int k = 2; k <= 8192; k <<= 1)
    for (int j = k >> 1; j > 0; j >>= 1) {
      for (int i = threadIdx.x; i < 8192; i += 1024) {
        const int p = i ^ j;
        if (p > i) {
          const unsigned long long a = skey[i], c = skey[p];
          const bool up = ((i & k) == 0);
          if ((a > c) == up) { skey[i] = c; skey[p] = a; }
        }
      }
      __syncthreads();
    }
  for (int r = threadIdx.x; r < KSEL; r += 1024) {
    const unsigned long long key = ~skey[r];
    sidx[b * KPAD + r] = 0xFFFFFFFFu - (unsigned)(key & 0xFFFFFFFFull);
  }
}

__global__ __launch_bounds__(256) void decode_kernel(const float* __restrict__ anchors,
                                                     const float* __restrict__ bbox,
                                                     const unsigned* __restrict__ sidx,
                                                     float4* __restrict__ boxes, int N) {
  const int b = blockIdx.y;
  const int j = blockIdx.x * 256 + (int)threadIdx.x;
  if (j >= KSEL) return;
  unsigned idx = sidx[b * KPAD + j];
  if (idx >= (unsigned)N) idx = 0;  // safety
  const float4 A = ((const float4*)anchors)[(size_t)b * N + idx];
  const float4 R = ((const float4*)bbox)[(size_t)b * N + idx];
  // exact f32 replication of reference (contract(off) is file-scope)
  const float d0 = R.x * 0.1f, d1 = R.y * 0.1f, d2 = R.z * 0.2f, d3 = R.w * 0.2f;
  const float h = A.z - A.x;
  const float w = A.w - A.y;
  const float cy = A.x + 0.5f * h + d0 * h;
  const float cx = A.y + 0.5f * w + d1 * w;
  const float e2 = (float)exp((double)d2);  // correctly-rounded f32 exp
  const float e3 = (float)exp((double)d3);
  const float h2 = h * e2;
  const float w2 = w * e3;
  float y1 = cy - 0.5f * h2;
  float x1 = cx - 0.5f * w2;
  float y2 = y1 + h2;
  float x2 = x1 + w2;
  y1 = fminf(fmaxf(y1, 0.0f), 1.0f);
  x1 = fminf(fmaxf(x1, 0.0f), 1.0f);
  y2 = fminf(fmaxf(y2, 0.0f), 1.0f);
  x2 = fminf(fmaxf(x2, 0.0f), 1.0f);
  boxes[b * KPAD + j] = make_float4(y1, x1, y2, x2);
}

// ---- bitmatrix NMS ----
// Row-major storage: mat[((b*KPAD) + i)*NWORDS + w] = 64 column-bits [w*64, w*64+64) of row i.
// Only words w >= i>>6 are written (upper triangle); bits c <= i are 0 in the diagonal word.
// One block per (image, 64-row tile): stages all words in LDS, then coalesced copy-out.
__global__ __launch_bounds__(256) void suppmat_kernel(const float4* __restrict__ boxes,
                                                      unsigned long long* __restrict__ mat) {
  const int b = blockIdx.y;
  const int it = blockIdx.x;            // row tile
  const int wv = threadIdx.x >> 6;
  const int lane = threadIdx.x & 63;
  const float4* gbox = boxes + b * KPAD;
  __shared__ float4 srow[64];
  __shared__ float sarea[64];
  __shared__ unsigned long long wbuf[64][NWORDS];   // 48128 B
  if (threadIdx.x < 64) {
    const float4 v = gbox[it * 64 + threadIdx.x];
    srow[threadIdx.x] = v;
    sarea[threadIdx.x] = (v.z - v.x) * (v.w - v.y);
  }
  __syncthreads();
  // wave's 16 rows into registers (uniform per lane)
  float4 rb[16]; float rba[16];
#pragma unroll
  for (int k = 0; k < 16; ++k) { rb[k] = srow[wv * 16 + k]; rba[k] = sarea[wv * 16 + k]; }
  const double M = 0.7000000178813934326171875;
  for (int jt = it; jt < NWORDS; ++jt) {
    const int c = jt * 64 + lane;
    const float4 cv = gbox[c];
    const float ca = (cv.z - cv.x) * (cv.w - cv.y);
#pragma unroll
    for (int k = 0; k < 16; ++k) {
      const int i = it * 64 + wv * 16 + k;
      const float4 hb = rb[k];
      const float ha = rba[k];
      const float iy1 = fmaxf(hb.x, cv.x);
      const float ix1 = fmaxf(hb.y, cv.y);
      const float iy2 = fminf(hb.z, cv.z);
      const float ix2 = fminf(hb.w, cv.w);
      const float dy = fmaxf(iy2 - iy1, 0.0f);
      const float dx = fmaxf(ix2 - ix1, 0.0f);
      const float inter = dy * dx;
      const float denom = ha + ca - inter + 1e-12f;
      const bool s = (c > i) && ((double)inter >= M * (double)denom);
      const unsigned long long w = __ballot(s);
      if (lane == 0) wbuf[wv * 16 + k][jt] = w;
    }
  }
  __syncthreads();
  const int nw = NWORDS - it;
  unsigned long long* obase = mat + ((size_t)b * KPAD + (size_t)it * 64) * NWORDS;
  for (int q = threadIdx.x; q < 64 * nw; q += 256) {
    const int r = q / nw;
    const int k = q - r * nw;
    obase[(size_t)r * NWORDS + it + k] = wbuf[r][it + k];
  }
}

// Window-batched exact greedy resolve. One block (1024 thr) per image.
// Per round: gather next <=64 alive indices (span-capped to 8 words); wave 0 loads each
// window row's 8-word segment coalesced, builds intra-window column masks in registers,
// replays greedy with bit-ops; all waves apply accepted rows' suppression to the tail.
__global__ __launch_bounds__(1024) void resolve_kernel(const Ctrl* __restrict__ ctrl,
                                                       const float4* __restrict__ boxes,
                                                       const unsigned long long* __restrict__ mat,
                                                       float* __restrict__ out) {
  const int b = blockIdx.x;
  const int tid = threadIdx.x;
  const int lane = tid & 63;
  const int wv = tid >> 6;
  int total = (int)ctrl[b].total; if (total > KSEL) total = KSEL;
  const unsigned long long* cmat = mat + (size_t)b * KPAD * NWORDS;
  const float4* gbox = boxes + b * KPAD;
  float4* outv = (float4*)(out + (size_t)b * PROP * 4);

  __shared__ unsigned long long smask[NWORDS];
  __shared__ int s_widx[64];
  __shared__ int s_heads[64];
  __shared__ int s_cnt, s_nAcc, s_total, s_cursor, s_wlast;

  for (int k = tid; k < NWORDS; k += 1024) {
    const int lo = k * 64;
    unsigned long long m = 0ull;
    if (lo < total) m = (total - lo >= 64) ? ~0ull : ((1ull << (total - lo)) - 1ull);
    smask[k] = m;
  }
  if (tid == 0) { s_total = 0; s_cursor = 0; }
  __syncthreads();

  for (;;) {
    // ---- gather next window (thread 0; bits below cursor are already cleared) ----
    if (tid == 0) {
      int cnt = 0, firstw = 0, last = -1;
      int w = s_cursor >> 6;
      unsigned long long word = (w < NWORDS) ? smask[w] : 0ull;
      while (cnt < 64 && w < NWORDS) {
        if (word == 0ull) { ++w; word = (w < NWORDS) ? smask[w] : 0ull; continue; }
        const int bit = __builtin_ctzll(word);
        const int idx = (w << 6) | bit;
        if (cnt > 0 && (idx >> 6) - firstw >= 8) break;  // cap row-segment to 8 words
        if (cnt == 0) firstw = idx >> 6;
        word &= word - 1ull;
        s_widx[cnt++] = idx;
        last = idx;
      }
      s_cnt = cnt;
      s_wlast = last;
      s_cursor = (cnt > 0) ? (last + 1) : (NWORDS * 64);
    }
    __syncthreads();  // B1
    const int cnt = s_cnt;
    if (cnt == 0) break;
    const int jlast = s_wlast;
    const int totalOld = s_total;

    // ---- window resolution: wave 0 ----
    if (wv == 0) {
      const int j = s_widx[(lane < cnt) ? lane : 0];
      const int w0 = s_widx[0] >> 6;
      const unsigned long long* rp = cmat + (size_t)j * NWORDS;
      unsigned long long rw[8];
#pragma unroll
      for (int k = 0; k < 8; ++k)
        rw[k] = (w0 + k < NWORDS) ? rp[w0 + k] : 0ull;
      // colmask bit m: row j suppresses window column m. Garbage below-diagonal words
      // only affect m <= lane, masked off below.
      unsigned long long colmask = 0ull;
      for (int m = 0; m < cnt; ++m) {
        const int jm = s_widx[m];
        const int rel = (jm >> 6) - w0;
        const int bit = jm & 63;
        unsigned long long x = rw[0];
        x = (rel == 1) ? rw[1] : x;
        x = (rel == 2) ? rw[2] : x;
        x = (rel == 3) ? rw[3] : x;
        x = (rel == 4) ? rw[4] : x;
        x = (rel == 5) ? rw[5] : x;
        x = (rel == 6) ? rw[6] : x;
        x = (rel == 7) ? rw[7] : x;
        colmask |= ((x >> bit) & 1ull) << m;
      }
      colmask = (lane < 63) ? (colmask & (~0ull << (lane + 1))) : 0ull;
      if (lane >= cnt) colmask = 0ull;
      // greedy replay (pure bit ops)
      unsigned long long aliveW = (cnt >= 64) ? ~0ull : ((1ull << cnt) - 1ull);
      unsigned long long acc = 0ull;
      for (int i = 0; i < cnt; ++i) {
        const unsigned long long cm = __shfl(colmask, i, 64);
        if ((aliveW >> i) & 1ull) { acc |= 1ull << i; aliveW &= ~cm; }
      }
      // budget truncation: keep earliest
      const int need = PROP - totalOld;
      int na = __popcll(acc);
      if (na > need) {
        unsigned long long t2 = acc, a2 = 0ull;
        for (int c2 = 0; c2 < need; ++c2) { a2 |= t2 & (0ull - t2); t2 &= t2 - 1ull; }
        acc = a2; na = need;
      }
      if (lane < cnt && ((acc >> lane) & 1ull)) {
        const int r = __popcll(acc & ((1ull << lane) - 1ull));
        outv[totalOld + r] = gbox[j];
        s_heads[r] = j;
      }
      if (lane == 0) {
        s_nAcc = na; s_total = totalOld + na;
        // range-clear: everything <= jlast is resolved
        const int wl = jlast >> 6;
        for (int w = w0; w < wl; ++w) smask[w] = 0ull;
        const unsigned long long keep = ((jlast & 63) == 63) ? 0ull : (~0ull << ((jlast & 63) + 1));
        smask[wl] &= keep;
      }
    }
    __syncthreads();  // B2
    if (s_total >= PROP) break;
    // ---- tail suppression: all waves, coalesced row reads, LDS atomicAnd ----
    const int na = s_nAcc;
    const int wT = jlast >> 6;
    const int nw = NWORDS - wT;
    const int grp = tid >> 7;      // 8 groups of 128 threads
    const int gt = tid & 127;
    if (gt < nw) {
      const int w = wT + gt;
      for (int r = grp; r < na; r += 8) {
        const unsigned long long rv = cmat[(size_t)s_heads[r] * NWORDS + w];
        if (rv) atomicAnd(&smask[w], ~rv);
      }
    }
    __syncthreads();  // B3
  }

  const int wtot = s_total;
  for (int k = wtot + tid; k < PROP; k += 1024) outv[k] = make_float4(0.f, 0.f, 0.f, 0.f);
}

// ---- fallback windowed NMS (round-2, known-passing) for small ws ----
__global__ __launch_bounds__(1024) void nms_kernel(const float4* __restrict__ boxes, float* __restrict__ out) {
  const int b = blockIdx.x;
  const int tid = threadIdx.x;
  const int lane = tid & 63;
  const float4* gbox = boxes + b * KPAD;
  float* outB = out + b * (PROP * 4);
  __shared__ unsigned long long smask[94];
  __shared__ int s_widx[64];
  __shared__ float4 s_wbox[64];
  __shared__ float s_wha[64];
  __shared__ int s_cnt, s_nAcc, s_total, s_cursor;
  for (int k = tid; k < 94; k += 1024)
    smask[k] = (k == 93) ? ((1ull << 48) - 1ull) : ~0ull;
  if (tid == 0) { s_cursor = 0; s_total = 0; }
  __syncthreads();
  const double M = 0.7000000178813934326171875;
  for (int round = 0; round < PROP; ++round) {
    if (tid == 0) {
      int cnt = 0;
      const int cur = s_cursor;
      int w = cur >> 6;
      unsigned long long word = (w < 94) ? (smask[w] & (~0ull << (cur & 63))) : 0ull;
      while (cnt < 64) {
        while (word == 0ull && ++w < 94) word = smask[w];
        if (w >= 94) break;
        const int bit = __builtin_ctzll(word);
        word &= word - 1ull;
        s_widx[cnt++] = (w << 6) | bit;
      }
      s_cnt = cnt;
      s_cursor = cnt ? (s_widx[cnt - 1] + 1) : KSEL;
    }
    __syncthreads();
    const int cnt = s_cnt;
    const int tailStart = s_cursor;
    if (cnt == 0) break;
    if (tid < 64) {
      const int j = (lane < cnt) ? s_widx[lane] : -1;
      float4 v = make_float4(0.f, 0.f, 0.f, 0.f);
      if (j >= 0) v = gbox[j];
      const float a = (v.z - v.x) * (v.w - v.y);
      const int totalOld = s_total;
      unsigned long long aliveW = __ballot(j >= 0);
      unsigned long long acc = 0ull;
      for (int i = 0; i < 64; ++i) {
        const float hx = __shfl(v.x, i), hy = __shfl(v.y, i);
        const float hz = __shfl(v.z, i), hw = __shfl(v.w, i);
        const float ha = __shfl(a, i);
        bool s = false;
        if (j >= 0 && lane > i) {
          const float iy1 = fmaxf(hx, v.x);
          const float ix1 = fmaxf(hy, v.y);
          const float iy2 = fminf(hz, v.z);
          const float ix2 = fminf(hw, v.w);
          const float dy = fmaxf(iy2 - iy1, 0.0f);
          const float dx = fmaxf(ix2 - ix1, 0.0f);
          const float inter = dy * dx;
          const float denom = ha + a - inter + 1e-12f;
          s = ((double)inter >= M * (double)denom);
        }
        const unsigned long long m = __ballot(s);
        if (aliveW & (1ull << i)) { acc |= 1ull << i; aliveW &= ~m; }
      }
      const int need = PROP - totalOld;
      int na = __popcll(acc);
      if (na > need) {
        unsigned long long t = acc, a2 = 0ull;
        for (int c2 = 0; c2 < need; ++c2) { a2 |= t & (0ull - t); t &= t - 1ull; }
        acc = a2; na = need;
      }
      if ((acc >> lane) & 1ull) {
        const int r = __popcll(acc & ((1ull << lane) - 1ull));
        float* o = outB + (size_t)(totalOld + r) * 4;
        o[0] = v.x; o[1] = v.y; o[2] = v.z; o[3] = v.w;
        s_wbox[r] = v; s_wha[r] = a;
      }
      if (lane == 0) { s_nAcc = na; s_total = totalOld + na; }
      if (j >= 0) atomicAnd(&smask[j >> 6], ~(1ull << (j & 63)));
    }
    __syncthreads();
    const int total = s_total;
    const int nAcc = s_nAcc;
    if (total >= PROP) break;
    for (int j = tailStart + tid; j < KSEL; j += 1024) {
      if (!((smask[j >> 6] >> (j & 63)) & 1ull)) continue;
      const float4 v = gbox[j];
      const float a = (v.z - v.x) * (v.w - v.y);
      bool supp = false;
      for (int r = 0; r < nAcc; ++r) {
        const float4 hb = s_wbox[r];
        const float ha = s_wha[r];
        const float iy1 = fmaxf(hb.x, v.x);
        const float ix1 = fmaxf(hb.y, v.y);
        const float iy2 = fminf(hb.z, v.z);
        const float ix2 = fminf(hb.w, v.w);
        const float dy = fmaxf(iy2 - iy1, 0.0f);
        const float dx = fmaxf(ix2 - ix1, 0.0f);
        const float inter = dy * dx;
        const float denom = ha + a - inter + 1e-12f;
        if ((double)inter >= M * (double)denom) { supp = true; break; }
      }
      if (supp) atomicAnd(&smask[j >> 6], ~(1ull << (j & 63)));
    }
    __syncthreads();
  }
  const int written = s_total;
  for (int u = written * 4 + tid; u < PROP * 4; u += 1024) outB[u] = 0.0f;
}

extern "C" void kernel_launch(void* const* d_in, const int* in_sizes, int n_in,
                              void* d_out, int out_size, void* d_ws, size_t ws_size,
                              hipStream_t stream) {
  (void)n_in; (void)out_size;
  const float* probs = (const float*)d_in[0];
  const float* bbox = (const float*)d_in[1];
  const float* anchors = (const float*)d_in[2];
  float* out = (float*)d_out;
  char* ws = (char*)d_ws;
  const int N = in_sizes[0] / (NB * 2);  // 261888

  unsigned* hist1 = (unsigned*)(ws + OFF_HIST1);
  unsigned* hist2 = (unsigned*)(ws + OFF_HIST2);
  unsigned* hist3 = (unsigned*)(ws + OFF_HIST3);
  Ctrl* ctrl = (Ctrl*)(ws + OFF_CTRL);
  unsigned long long* sel = (unsigned long long*)(ws + OFF_SEL);
  unsigned* eqBuf = (unsigned*)(ws + OFF_EQ);
  unsigned* sidx = (unsigned*)(ws + OFF_SIDX);
  float4* boxes = (float4*)(ws + OFF_BOX);
  unsigned long long* mat = (unsigned long long*)(ws + OFF_MAT);

  const int zeroN = (int)(OFF_SEL / 4);  // hist1+hist2+hist3+ctrl
  zero_kernel<<<dim3((zeroN + 255) / 256), dim3(256), 0, stream>>>((unsigned*)ws, zeroN);

  const int gx = (N + 16383) / 16384;
  hist_kernel<<<dim3(gx, NB), dim3(256), 0, stream>>>(1, probs, hist1, ctrl, N);
  scan_kernel<<<dim3(NB), dim3(64), 0, stream>>>(1, hist1, ctrl);
  hist_kernel<<<dim3(gx, NB), dim3(256), 0, stream>>>(2, probs, hist2, ctrl, N);
  scan_kernel<<<dim3(NB), dim3(64), 0, stream>>>(2, hist2, ctrl);
  hist_kernel<<<dim3(gx, NB), dim3(256), 0, stream>>>(3, probs, hist3, ctrl, N);
  scan_kernel<<<dim3(NB), dim3(64), 0, stream>>>(3, hist3, ctrl);
  compact_kernel<<<dim3(gx, NB), dim3(256), 0, stream>>>(probs, ctrl, sel, eqBuf, N);
  eqres_kernel<<<dim3(NB), dim3(256), 0, stream>>>(ctrl, eqBuf, sel);
  sort_kernel<<<dim3(NB), dim3(1024), 0, stream>>>(ctrl, sel, sidx);
  decode_kernel<<<dim3((KSEL + 255) / 256, NB), dim3(256), 0, stream>>>(anchors, bbox, sidx, boxes, N);

  if (ws_size >= (size_t)OFF_MAT + MAT_BYTES) {
    suppmat_kernel<<<dim3(NTILE, NB), dim3(256), 0, stream>>>(boxes, mat);
    resolve_kernel<<<dim3(NB), dim3(1024), 0, stream>>>(ctrl, boxes, mat, out);
  } else {
    nms_kernel<<<dim3(NB), dim3(1024), 0, stream>>>(boxes, out);
  }
}

// Round 5
// 615.630 us; speedup vs baseline: 2.8266x; 1.2146x over previous
//
#include <hip/hip_runtime.h>

#pragma clang fp contract(off)

#define NB 8
#define KSEL 6000
#define KPAD 6016
#define PROP 1000
#define EQCAP 8192
#define NWORDS 94
#define NTILE 94
#define RT 768

// ws layout (bytes)
#define OFF_HIST1 0u          // 8*4096*4 = 131072
#define OFF_HIST2 131072u     // 8*4096*4
#define OFF_HIST3 262144u     // 8*256*4 = 8192
#define OFF_CTRL  270336u     // 8*64 = 512
#define OFF_SEL   270848u     // 8*6016*8 = 385024
#define OFF_EQ    655872u     // 8*8192*4 = 262144
#define OFF_SIDX  918016u     // 8*6016*4 = 192512
#define OFF_BOX   1110528u    // 8*6016*16 = 770048 -> end 1880576
#define OFF_MAT   1884160u    // 8*6016*94*8 = 36192256 -> end 38076416
#define MAT_BYTES 36192256ull

struct Ctrl {
  unsigned t1, rem1, t2, rem2, thr, needEq, selCount, eqCount, total;
  unsigned pad[7];
};

__global__ __launch_bounds__(256) void zero_kernel(unsigned* p, int n) {
  int i = blockIdx.x * 256 + threadIdx.x;
  if (i < n) p[i] = 0u;
}

// phase 1: bin = bits>>20 (4096 bins); phase 2: mid 12 bits within t1; phase 3: low 8 bits within (t1,t2)
__global__ __launch_bounds__(256) void hist_kernel(int phase, const float* __restrict__ probs,
                                                   unsigned* __restrict__ hist,
                                                   const Ctrl* __restrict__ ctrl, int N) {
  __shared__ unsigned lh[4096];
  const int b = blockIdx.y;
  const int nb = (phase == 3) ? 256 : 4096;
  for (int k = threadIdx.x; k < nb; k += 256) lh[k] = 0u;
  unsigned t1 = 0, pre24 = 0;
  if (phase == 2) t1 = ctrl[b].t1;
  if (phase == 3) pre24 = (ctrl[b].t1 << 12) | ctrl[b].t2;
  __syncthreads();
  const int start = blockIdx.x * 16384;
  const int end = min(start + 16384, N);
  for (int i = start + (int)threadIdx.x; i < end; i += 256) {
    const unsigned bits = __float_as_uint(probs[(size_t)(b * N + i) * 2 + 1]);
    if (phase == 1) atomicAdd(&lh[bits >> 20], 1u);
    else if (phase == 2) { if ((bits >> 20) == t1) atomicAdd(&lh[(bits >> 8) & 0xFFFu], 1u); }
    else { if ((bits >> 8) == pre24) atomicAdd(&lh[bits & 0xFFu], 1u); }
  }
  __syncthreads();
  for (int k = threadIdx.x; k < nb; k += 256) {
    const unsigned v = lh[k];
    if (v) atomicAdd(&hist[b * nb + k], v);
  }
}

// one wave per image: descending cumulative scan, find threshold bin
__global__ __launch_bounds__(64) void scan_kernel(int phase, const unsigned* __restrict__ hist,
                                                  Ctrl* __restrict__ ctrl) {
  const int b = blockIdx.x;
  const int lane = threadIdx.x;
  const int nb = (phase == 3) ? 256 : 4096;
  const int chunks = nb >> 6;
  const unsigned target = (phase == 1) ? 6000u : ((phase == 2) ? ctrl[b].rem1 : ctrl[b].rem2);
  const unsigned* h = hist + b * nb;
  const int topbin = nb - 1 - lane * chunks;
  unsigned mysum = 0;
  for (int c = 0; c < chunks; c++) mysum += h[topbin - c];
  unsigned cum = mysum;
  for (int off = 1; off < 64; off <<= 1) {
    const unsigned v = __shfl_up(cum, off, 64);
    if (lane >= off) cum += v;
  }
  const unsigned prev = cum - mysum;
  if (prev < target && cum >= target) {
    unsigned c2 = prev;
    for (int c = 0; c < chunks; c++) {
      const int bin = topbin - c;
      const unsigned hv = h[bin];
      if (c2 + hv >= target) {
        const unsigned rem = target - c2;
        if (phase == 1) { ctrl[b].t1 = (unsigned)bin; ctrl[b].rem1 = rem; }
        else if (phase == 2) { ctrl[b].t2 = (unsigned)bin; ctrl[b].rem2 = rem; }
        else {
          ctrl[b].thr = (ctrl[b].t1 << 20) | (ctrl[b].t2 << 8) | (unsigned)bin;
          ctrl[b].needEq = rem;
        }
        break;
      }
      c2 += hv;
    }
  }
}

__global__ __launch_bounds__(256) void compact_kernel(const float* __restrict__ probs, Ctrl* __restrict__ ctrl,
                                                      unsigned long long* __restrict__ sel,
                                                      unsigned* __restrict__ eqBuf, int N) {
  const int b = blockIdx.y;
  const unsigned THR = ctrl[b].thr;
  const int start = blockIdx.x * 16384;
  const int end = min(start + 16384, N);
  const int lane = threadIdx.x & 63;
  const int iters = (end - start + 255) / 256;
  for (int it = 0; it < iters; it++) {
    const int i = start + it * 256 + (int)threadIdx.x;
    const bool v = i < end;
    unsigned bits = 0u;
    if (v) bits = __float_as_uint(probs[(size_t)(b * N + i) * 2 + 1]);
    const bool gt = v && (bits > THR);
    const bool eq = v && (bits == THR);
    const unsigned long long mg = __ballot(gt);
    if (mg) {
      const int leader = __builtin_ctzll(mg);
      unsigned base = 0;
      if (lane == leader) base = atomicAdd(&ctrl[b].selCount, (unsigned)__builtin_popcountll(mg));
      base = (unsigned)__shfl((int)base, leader, 64);
      if (gt) {
        const int rank = __builtin_popcountll(mg & ((1ull << lane) - 1ull));
        const unsigned pos = base + (unsigned)rank;
        if (pos < (unsigned)KPAD) sel[b * KPAD + pos] = ((unsigned long long)bits << 32) | (unsigned)i;
      }
    }
    const unsigned long long me = __ballot(eq);
    if (me) {
      const int leader = __builtin_ctzll(me);
      unsigned base = 0;
      if (lane == leader) base = atomicAdd(&ctrl[b].eqCount, (unsigned)__builtin_popcountll(me));
      base = (unsigned)__shfl((int)base, leader, 64);
      if (eq) {
        const int rank = __builtin_popcountll(me & ((1ull << lane) - 1ull));
        const unsigned pos = base + (unsigned)rank;
        if (pos < (unsigned)EQCAP) eqBuf[b * EQCAP + pos] = (unsigned)i;
      }
    }
  }
}

// resolve ties at the exact threshold: take lowest indices
__global__ __launch_bounds__(256) void eqres_kernel(Ctrl* __restrict__ ctrl, const unsigned* __restrict__ eqBuf,
                                                    unsigned long long* __restrict__ sel) {
  __shared__ unsigned si[EQCAP];
  const int b = blockIdx.x;
  const unsigned need = ctrl[b].needEq;
  unsigned cnt = ctrl[b].eqCount; if (cnt > EQCAP) cnt = EQCAP;
  const unsigned base = ctrl[b].selCount;
  const unsigned long long thrHi = ((unsigned long long)ctrl[b].thr) << 32;
  if (cnt <= need) {
    for (unsigned e = threadIdx.x; e < cnt; e += 256)
      sel[b * KPAD + base + e] = thrHi | (unsigned long long)eqBuf[b * EQCAP + e];
    if (threadIdx.x == 0) ctrl[b].total = base + cnt;
  } else {
    for (int k = threadIdx.x; k < EQCAP; k += 256)
      si[k] = (k < (int)cnt) ? eqBuf[b * EQCAP + k] : 0xFFFFFFFFu;
    __syncthreads();
    for (int k = 2; k <= EQCAP; k <<= 1)
      for (int j = k >> 1; j > 0; j >>= 1) {
        for (int idx = threadIdx.x; idx < EQCAP; idx += 256) {
          const int p = idx ^ j;
          if (p > idx) {
            const unsigned a = si[idx], c = si[p];
            const bool up = ((idx & k) == 0);
            if ((a > c) == up) { si[idx] = c; si[p] = a; }
          }
        }
        __syncthreads();
      }
    for (unsigned e = threadIdx.x; e < need; e += 256)
      sel[b * KPAD + base + e] = thrHi | (unsigned long long)si[e];
    if (threadIdx.x == 0) ctrl[b].total = base + need;
  }
}

// Pairwise rank: replaces the bitonic sort. key = (scorebits<<32) | ~idx; rank = #{keys > mine}.
// Block (tile, image): stage all 6016 keys in LDS; each wave counts one quarter for 64 elements.
__global__ __launch_bounds__(256) void rank_kernel(const Ctrl* __restrict__ ctrl,
                                                   const unsigned long long* __restrict__ sel,
                                                   unsigned* __restrict__ sidx) {
  const int b = blockIdx.y;
  const int it = blockIdx.x;     // 0..93
  const int tid = threadIdx.x;
  const int wv = tid >> 6, lane = tid & 63;
  __shared__ unsigned long long skey[KPAD];   // 48128 B
  __shared__ unsigned scnt[4][64];
  int total = (int)ctrl[b].total; if (total > KSEL) total = KSEL;
  for (int i = tid; i < KPAD; i += 256) {
    unsigned long long kp = 0ull;
    if (i < total) {
      const unsigned long long e = sel[b * KPAD + i];
      kp = (e & 0xFFFFFFFF00000000ull) | (unsigned long long)(0xFFFFFFFFu - (unsigned)e);
    }
    skey[i] = kp;
  }
  __syncthreads();
  const int me = it * 64 + lane;               // < 6016
  const unsigned long long myk = skey[me];
  const int chunk = KPAD / 4;                  // 1504
  const int lo = wv * chunk;
  unsigned cnt = 0;
#pragma unroll 8
  for (int c = 0; c < chunk; ++c) cnt += (skey[lo + c] > myk) ? 1u : 0u;
  scnt[wv][lane] = cnt;
  __syncthreads();
  if (wv == 0 && me < total) {
    const unsigned rank = scnt[0][lane] + scnt[1][lane] + scnt[2][lane] + scnt[3][lane];
    sidx[b * KPAD + rank] = 0xFFFFFFFFu - (unsigned)myk;
  }
}

__global__ __launch_bounds__(256) void decode_kernel(const float* __restrict__ anchors,
                                                     const float* __restrict__ bbox,
                                                     const unsigned* __restrict__ sidx,
                                                     float4* __restrict__ boxes, int N) {
  const int b = blockIdx.y;
  const int j = blockIdx.x * 256 + (int)threadIdx.x;
  if (j >= KSEL) return;
  unsigned idx = sidx[b * KPAD + j];
  if (idx >= (unsigned)N) idx = 0;  // safety
  const float4 A = ((const float4*)anchors)[(size_t)b * N + idx];
  const float4 R = ((const float4*)bbox)[(size_t)b * N + idx];
  // exact f32 replication of reference (contract(off) is file-scope)
  const float d0 = R.x * 0.1f, d1 = R.y * 0.1f, d2 = R.z * 0.2f, d3 = R.w * 0.2f;
  const float h = A.z - A.x;
  const float w = A.w - A.y;
  const float cy = A.x + 0.5f * h + d0 * h;
  const float cx = A.y + 0.5f * w + d1 * w;
  const float e2 = (float)exp((double)d2);  // correctly-rounded f32 exp
  const float e3 = (float)exp((double)d3);
  const float h2 = h * e2;
  const float w2 = w * e3;
  float y1 = cy - 0.5f * h2;
  float x1 = cx - 0.5f * w2;
  float y2 = y1 + h2;
  float x2 = x1 + w2;
  y1 = fminf(fmaxf(y1, 0.0f), 1.0f);
  x1 = fminf(fmaxf(x1, 0.0f), 1.0f);
  y2 = fminf(fmaxf(y2, 0.0f), 1.0f);
  x2 = fminf(fmaxf(x2, 0.0f), 1.0f);
  boxes[b * KPAD + j] = make_float4(y1, x1, y2, x2);
}

// ---- bitmatrix NMS ----
// Row-major storage: mat[((b*KPAD) + i)*NWORDS + w] = 64 column-bits [w*64, w*64+64) of row i.
// Only words w >= i>>6 are written (upper triangle); bits c <= i are 0 in the diagonal word.
__global__ __launch_bounds__(256) void suppmat_kernel(const float4* __restrict__ boxes,
                                                      unsigned long long* __restrict__ mat) {
  const int b = blockIdx.y;
  const int it = blockIdx.x;            // row tile
  const int wv = threadIdx.x >> 6;
  const int lane = threadIdx.x & 63;
  const float4* gbox = boxes + b * KPAD;
  __shared__ float4 srow[64];
  __shared__ float sarea[64];
  __shared__ unsigned long long wbuf[64][NWORDS];   // 48128 B
  if (threadIdx.x < 64) {
    const float4 v = gbox[it * 64 + threadIdx.x];
    srow[threadIdx.x] = v;
    sarea[threadIdx.x] = (v.z - v.x) * (v.w - v.y);
  }
  __syncthreads();
  float4 rb[16]; float rba[16];
#pragma unroll
  for (int k = 0; k < 16; ++k) { rb[k] = srow[wv * 16 + k]; rba[k] = sarea[wv * 16 + k]; }
  const double M = 0.7000000178813934326171875;
  for (int jt = it; jt < NWORDS; ++jt) {
    const int c = jt * 64 + lane;
    const float4 cv = gbox[c];
    const float ca = (cv.z - cv.x) * (cv.w - cv.y);
#pragma unroll
    for (int k = 0; k < 16; ++k) {
      const int i = it * 64 + wv * 16 + k;
      const float4 hb = rb[k];
      const float ha = rba[k];
      const float iy1 = fmaxf(hb.x, cv.x);
      const float ix1 = fmaxf(hb.y, cv.y);
      const float iy2 = fminf(hb.z, cv.z);
      const float ix2 = fminf(hb.w, cv.w);
      const float dy = fmaxf(iy2 - iy1, 0.0f);
      const float dx = fmaxf(ix2 - ix1, 0.0f);
      const float inter = dy * dx;
      const float denom = ha + ca - inter + 1e-12f;
      const bool s = (c > i) && ((double)inter >= M * (double)denom);
      const unsigned long long w = __ballot(s);
      if (lane == 0) wbuf[wv * 16 + k][jt] = w;
    }
  }
  __syncthreads();
  const int nw = NWORDS - it;
  unsigned long long* obase = mat + ((size_t)b * KPAD + (size_t)it * 64) * NWORDS;
  for (int q = threadIdx.x; q < 64 * nw; q += 256) {
    const int r = q / nw;
    const int k = q - r * nw;
    obase[(size_t)r * NWORDS + it + k] = wbuf[r][it + k];
  }
}

// Window-batched exact greedy resolve, MLP-optimized. One 768-thread block per image.
__global__ __launch_bounds__(768) void resolve_kernel(const Ctrl* __restrict__ ctrl,
                                                      const float4* __restrict__ boxes,
                                                      const unsigned long long* __restrict__ mat,
                                                      float* __restrict__ out) {
  const int b = blockIdx.x;
  const int tid = threadIdx.x;
  const int lane = tid & 63;
  const int wv = tid >> 6;
  int total = (int)ctrl[b].total; if (total > KSEL) total = KSEL;
  const unsigned long long* cmat = mat + (size_t)b * KPAD * NWORDS;
  const float4* gbox = boxes + b * KPAD;
  float4* outv = (float4*)(out + (size_t)b * PROP * 4);

  __shared__ unsigned long long smask[NWORDS];
  __shared__ unsigned long long s_colmask[64];
  __shared__ int s_widx[64];
  __shared__ int s_heads[64];
  __shared__ int s_cnt, s_nAcc, s_total, s_cursor, s_wlast;

  for (int k = tid; k < NWORDS; k += RT) {
    const int lo = k * 64;
    unsigned long long m = 0ull;
    if (lo < total) m = (total - lo >= 64) ? ~0ull : ((1ull << (total - lo)) - 1ull);
    smask[k] = m;
  }
  if (tid == 0) { s_total = 0; s_cursor = 0; }
  __syncthreads();

  for (;;) {
    // ---- gather next window (thread 0; bits below cursor are already cleared) ----
    if (tid == 0) {
      int cnt = 0, firstw = 0, last = -1;
      int w = s_cursor >> 6;
      unsigned long long word = (w < NWORDS) ? smask[w] : 0ull;
      while (cnt < 64 && w < NWORDS) {
        if (word == 0ull) { ++w; word = (w < NWORDS) ? smask[w] : 0ull; continue; }
        const int bit = __builtin_ctzll(word);
        const int idx = (w << 6) | bit;
        if (cnt > 0 && (idx >> 6) - firstw >= 8) break;  // cap row-segment to 8 words
        if (cnt == 0) firstw = idx >> 6;
        word &= word - 1ull;
        s_widx[cnt++] = idx;
        last = idx;
      }
      s_cnt = cnt;
      s_wlast = last;
      s_cursor = (cnt > 0) ? (last + 1) : (NWORDS * 64);
    }
    __syncthreads();  // B1
    const int cnt = s_cnt;
    if (cnt == 0) break;
    const int jlast = s_wlast;
    const int totalOld = s_total;

    // ---- window resolution: wave 0 ----
    if (wv == 0) {
      const int j = s_widx[(lane < cnt) ? lane : 0];
      const int w0 = s_widx[0] >> 6;
      const unsigned long long* rp = cmat + (size_t)j * NWORDS;
      unsigned long long rw[8];
#pragma unroll
      for (int k = 0; k < 8; ++k)
        rw[k] = (w0 + k < NWORDS) ? rp[w0 + k] : 0ull;
      // colmask bit m: row j suppresses window column m. Garbage below-diagonal words
      // only affect m <= lane, masked off below.
      unsigned long long colmask = 0ull;
      for (int m = 0; m < cnt; ++m) {
        const int jm = s_widx[m];
        const int rel = (jm >> 6) - w0;
        const int bit = jm & 63;
        unsigned long long x = rw[0];
        x = (rel == 1) ? rw[1] : x;
        x = (rel == 2) ? rw[2] : x;
        x = (rel == 3) ? rw[3] : x;
        x = (rel == 4) ? rw[4] : x;
        x = (rel == 5) ? rw[5] : x;
        x = (rel == 6) ? rw[6] : x;
        x = (rel == 7) ? rw[7] : x;
        colmask |= ((x >> bit) & 1ull) << m;
      }
      colmask = (lane < 63) ? (colmask & (~0ull << (lane + 1))) : 0ull;
      if (lane >= cnt) colmask = 0ull;
      s_colmask[lane] = colmask;
      // same-wave LDS readback; greedy replay redundantly in every lane (branchless)
      unsigned long long aliveW = (cnt >= 64) ? ~0ull : ((1ull << cnt) - 1ull);
      unsigned long long acc = 0ull;
#pragma unroll
      for (int i = 0; i < 64; ++i) {
        const unsigned long long cm = s_colmask[i];
        const unsigned long long take = 0ull - ((aliveW >> i) & 1ull);
        acc |= ((1ull << i) & take);
        aliveW &= ~(cm & take);
      }
      // budget truncation: keep earliest
      const int need = PROP - totalOld;
      int na = __popcll(acc);
      if (na > need) {
        unsigned long long t2 = acc, a2 = 0ull;
        for (int c2 = 0; c2 < need; ++c2) { a2 |= t2 & (0ull - t2); t2 &= t2 - 1ull; }
        acc = a2; na = need;
      }
      if (lane < cnt && ((acc >> lane) & 1ull)) {
        const int r = __popcll(acc & ((1ull << lane) - 1ull));
        outv[totalOld + r] = gbox[j];
        s_heads[r] = j;
      }
      if (lane == 0) {
        s_nAcc = na; s_total = totalOld + na;
        // range-clear: everything <= jlast is resolved
        const int wl = jlast >> 6;
        for (int w = w0; w < wl; ++w) smask[w] = 0ull;
        const unsigned long long keep = ((jlast & 63) == 63) ? 0ull : (~0ull << ((jlast & 63) + 1));
        smask[wl] &= keep;
      }
    }
    __syncthreads();  // B2
    if (s_total >= PROP) break;

    // ---- tail suppression: (word, 8-row-group) per thread; 8 independent loads each ----
    const int na = s_nAcc;
    const int wT = jlast >> 6;
    const int nw = NWORDS - wT;
    if (tid < (nw << 3)) {
      const int w = wT + (tid >> 3);
      const int g = tid & 7;
      unsigned long long orv = 0ull;
#pragma unroll
      for (int k = 0; k < 8; ++k) {
        const int r = g + (k << 3);
        const unsigned long long rv = cmat[(size_t)s_heads[(r < na) ? r : 0] * NWORDS + w];
        orv |= (r < na) ? rv : 0ull;
      }
      if (orv) atomicAnd(&smask[w], ~orv);
    }
    __syncthreads();  // B3
  }

  const int wtot = s_total;
  for (int k = wtot + tid; k < PROP; k += RT) outv[k] = make_float4(0.f, 0.f, 0.f, 0.f);
}

// ---- fallback windowed NMS (round-2, known-passing) for small ws ----
__global__ __launch_bounds__(1024) void nms_kernel(const float4* __restrict__ boxes, float* __restrict__ out) {
  const int b = blockIdx.x;
  const int tid = threadIdx.x;
  const int lane = tid & 63;
  const float4* gbox = boxes + b * KPAD;
  float* outB = out + b * (PROP * 4);
  __shared__ unsigned long long smask[94];
  __shared__ int s_widx[64];
  __shared__ float4 s_wbox[64];
  __shared__ float s_wha[64];
  __shared__ int s_cnt, s_nAcc, s_total, s_cursor;
  for (int k = tid; k < 94; k += 1024)
    smask[k] = (k == 93) ? ((1ull << 48) - 1ull) : ~0ull;
  if (tid == 0) { s_cursor = 0; s_total = 0; }
  __syncthreads();
  const double M = 0.7000000178813934326171875;
  for (int round = 0; round < PROP; ++round) {
    if (tid == 0) {
      int cnt = 0;
      const int cur = s_cursor;
      int w = cur >> 6;
      unsigned long long word = (w < 94) ? (smask[w] & (~0ull << (cur & 63))) : 0ull;
      while (cnt < 64) {
        while (word == 0ull && ++w < 94) word = smask[w];
        if (w >= 94) break;
        const int bit = __builtin_ctzll(word);
        word &= word - 1ull;
        s_widx[cnt++] = (w << 6) | bit;
      }
      s_cnt = cnt;
      s_cursor = cnt ? (s_widx[cnt - 1] + 1) : KSEL;
    }
    __syncthreads();
    const int cnt = s_cnt;
    const int tailStart = s_cursor;
    if (cnt == 0) break;
    if (tid < 64) {
      const int j = (lane < cnt) ? s_widx[lane] : -1;
      float4 v = make_float4(0.f, 0.f, 0.f, 0.f);
      if (j >= 0) v = gbox[j];
      const float a = (v.z - v.x) * (v.w - v.y);
      const int totalOld = s_total;
      unsigned long long aliveW = __ballot(j >= 0);
      unsigned long long acc = 0ull;
      for (int i = 0; i < 64; ++i) {
        const float hx = __shfl(v.x, i), hy = __shfl(v.y, i);
        const float hz = __shfl(v.z, i), hw = __shfl(v.w, i);
        const float ha = __shfl(a, i);
        bool s = false;
        if (j >= 0 && lane > i) {
          const float iy1 = fmaxf(hx, v.x);
          const float ix1 = fmaxf(hy, v.y);
          const float iy2 = fminf(hz, v.z);
          const float ix2 = fminf(hw, v.w);
          const float dy = fmaxf(iy2 - iy1, 0.0f);
          const float dx = fmaxf(ix2 - ix1, 0.0f);
          const float inter = dy * dx;
          const float denom = ha + a - inter + 1e-12f;
          s = ((double)inter >= M * (double)denom);
        }
        const unsigned long long m = __ballot(s);
        if (aliveW & (1ull << i)) { acc |= 1ull << i; aliveW &= ~m; }
      }
      const int need = PROP - totalOld;
      int na = __popcll(acc);
      if (na > need) {
        unsigned long long t = acc, a2 = 0ull;
        for (int c2 = 0; c2 < need; ++c2) { a2 |= t & (0ull - t); t &= t - 1ull; }
        acc = a2; na = need;
      }
      if ((acc >> lane) & 1ull) {
        const int r = __popcll(acc & ((1ull << lane) - 1ull));
        float* o = outB + (size_t)(totalOld + r) * 4;
        o[0] = v.x; o[1] = v.y; o[2] = v.z; o[3] = v.w;
        s_wbox[r] = v; s_wha[r] = a;
      }
      if (lane == 0) { s_nAcc = na; s_total = totalOld + na; }
      if (j >= 0) atomicAnd(&smask[j >> 6], ~(1ull << (j & 63)));
    }
    __syncthreads();
    const int total = s_total;
    const int nAcc = s_nAcc;
    if (total >= PROP) break;
    for (int j = tailStart + tid; j < KSEL; j += 1024) {
      if (!((smask[j >> 6] >> (j & 63)) & 1ull)) continue;
      const float4 v = gbox[j];
      const float a = (v.z - v.x) * (v.w - v.y);
      bool supp = false;
      for (int r = 0; r < nAcc; ++r) {
        const float4 hb = s_wbox[r];
        const float ha = s_wha[r];
        const float iy1 = fmaxf(hb.x, v.x);
        const float ix1 = fmaxf(hb.y, v.y);
        const float iy2 = fminf(hb.z, v.z);
        const float ix2 = fminf(hb.w, v.w);
        const float dy = fmaxf(iy2 - iy1, 0.0f);
        const float dx = fmaxf(ix2 - ix1, 0.0f);
        const float inter = dy * dx;
        const float denom = ha + a - inter + 1e-12f;
        if ((double)inter >= M * (double)denom) { supp = true; break; }
      }
      if (supp) atomicAnd(&smask[j >> 6], ~(1ull << (j & 63)));
    }
    __syncthreads();
  }
  const int written = s_total;
  for (int u = written * 4 + tid; u < PROP * 4; u += 1024) outB[u] = 0.0f;
}

extern "C" void kernel_launch(void* const* d_in, const int* in_sizes, int n_in,
                              void* d_out, int out_size, void* d_ws, size_t ws_size,
                              hipStream_t stream) {
  (void)n_in; (void)out_size;
  const float* probs = (const float*)d_in[0];
  const float* bbox = (const float*)d_in[1];
  const float* anchors = (const float*)d_in[2];
  float* out = (float*)d_out;
  char* ws = (char*)d_ws;
  const int N = in_sizes[0] / (NB * 2);  // 261888

  unsigned* hist1 = (unsigned*)(ws + OFF_HIST1);
  unsigned* hist2 = (unsigned*)(ws + OFF_HIST2);
  unsigned* hist3 = (unsigned*)(ws + OFF_HIST3);
  Ctrl* ctrl = (Ctrl*)(ws + OFF_CTRL);
  unsigned long long* sel = (unsigned long long*)(ws + OFF_SEL);
  unsigned* eqBuf = (unsigned*)(ws + OFF_EQ);
  unsigned* sidx = (unsigned*)(ws + OFF_SIDX);
  float4* boxes = (float4*)(ws + OFF_BOX);
  unsigned long long* mat = (unsigned long long*)(ws + OFF_MAT);

  const int zeroN = (int)(OFF_SEL / 4);  // hist1+hist2+hist3+ctrl
  zero_kernel<<<dim3((zeroN + 255) / 256), dim3(256), 0, stream>>>((unsigned*)ws, zeroN);

  const int gx = (N + 16383) / 16384;
  hist_kernel<<<dim3(gx, NB), dim3(256), 0, stream>>>(1, probs, hist1, ctrl, N);
  scan_kernel<<<dim3(NB), dim3(64), 0, stream>>>(1, hist1, ctrl);
  hist_kernel<<<dim3(gx, NB), dim3(256), 0, stream>>>(2, probs, hist2, ctrl, N);
  scan_kernel<<<dim3(NB), dim3(64), 0, stream>>>(2, hist2, ctrl);
  hist_kernel<<<dim3(gx, NB), dim3(256), 0, stream>>>(3, probs, hist3, ctrl, N);
  scan_kernel<<<dim3(NB), dim3(64), 0, stream>>>(3, hist3, ctrl);
  compact_kernel<<<dim3(gx, NB), dim3(256), 0, stream>>>(probs, ctrl, sel, eqBuf, N);
  eqres_kernel<<<dim3(NB), dim3(256), 0, stream>>>(ctrl, eqBuf, sel);
  rank_kernel<<<dim3(NTILE, NB), dim3(256), 0, stream>>>(ctrl, sel, sidx);
  decode_kernel<<<dim3((KSEL + 255) / 256, NB), dim3(256), 0, stream>>>(anchors, bbox, sidx, boxes, N);

  if (ws_size >= (size_t)OFF_MAT + MAT_BYTES) {
    suppmat_kernel<<<dim3(NTILE, NB), dim3(256), 0, stream>>>(boxes, mat);
    resolve_kernel<<<dim3(NB), dim3(768), 0, stream>>>(ctrl, boxes, mat, out);
  } else {
    nms_kernel<<<dim3(NB), dim3(1024), 0, stream>>>(boxes, out);
  }
}

// Round 6
// 435.762 us; speedup vs baseline: 3.9933x; 1.4128x over previous
//
#include <hip/hip_runtime.h>

#pragma clang fp contract(off)

#define NB 8
#define KSEL 6000
#define KPAD 6016
#define PROP 1000
#define EQCAP 8192
#define NWORDS 94
#define NTILE 94
#define RT 768

// ws layout (bytes)
#define OFF_HIST1 0u          // 8*4096*4 = 131072
#define OFF_HIST2 131072u     // 8*4096*4
#define OFF_HIST3 262144u     // 8*256*4 = 8192
#define OFF_CTRL  270336u     // 8*64 = 512
#define OFF_SEL   270848u     // 8*6016*8 = 385024
#define OFF_EQ    655872u     // 8*8192*4 = 262144
#define OFF_SIDX  918016u     // (unused now)
#define OFF_BOX   1110528u    // 8*6016*16 = 770048 -> end 1880576
#define OFF_MAT   1884160u    // 8*6016*94*8 = 36192256 -> end 38076416
#define MAT_BYTES 36192256ull

struct Ctrl {
  unsigned t1, rem1, t2, rem2, thr, needEq, selCount, eqCount, total;
  unsigned pad[7];
};

__global__ __launch_bounds__(256) void zero_kernel(unsigned* p, int n) {
  int i = blockIdx.x * 256 + threadIdx.x;
  if (i < n) p[i] = 0u;
}

// phase 1: bin = bits>>20 (4096 bins); phase 2: mid 12 bits within t1; phase 3: low 8 bits within (t1,t2)
// 64 blocks/image x 256 thr; float4 loads carry two elements' fg scores (.y, .w).
__global__ __launch_bounds__(256) void hist_kernel(int phase, const float* __restrict__ probs,
                                                   unsigned* __restrict__ hist,
                                                   const Ctrl* __restrict__ ctrl, int N) {
  __shared__ unsigned lh[4096];
  const int b = blockIdx.y;
  const int nb = (phase == 3) ? 256 : 4096;
  for (int k = threadIdx.x; k < nb; k += 256) lh[k] = 0u;
  unsigned t1 = 0, pre24 = 0;
  if (phase == 2) t1 = ctrl[b].t1;
  if (phase == 3) pre24 = (ctrl[b].t1 << 12) | ctrl[b].t2;
  __syncthreads();
  const int start = blockIdx.x * 4096;
  const int end = min(start + 4096, N);
  for (int i = start + (int)threadIdx.x * 2; i < end; i += 512) {
    const float4 p2 = *(const float4*)(probs + ((size_t)b * N + i) * 2);
    const unsigned bits0 = __float_as_uint(p2.y);
    if (phase == 1) atomicAdd(&lh[bits0 >> 20], 1u);
    else if (phase == 2) { if ((bits0 >> 20) == t1) atomicAdd(&lh[(bits0 >> 8) & 0xFFFu], 1u); }
    else { if ((bits0 >> 8) == pre24) atomicAdd(&lh[bits0 & 0xFFu], 1u); }
    if (i + 1 < end) {
      const unsigned bits1 = __float_as_uint(p2.w);
      if (phase == 1) atomicAdd(&lh[bits1 >> 20], 1u);
      else if (phase == 2) { if ((bits1 >> 20) == t1) atomicAdd(&lh[(bits1 >> 8) & 0xFFFu], 1u); }
      else { if ((bits1 >> 8) == pre24) atomicAdd(&lh[bits1 & 0xFFu], 1u); }
    }
  }
  __syncthreads();
  for (int k = threadIdx.x; k < nb; k += 256) {
    const unsigned v = lh[k];
    if (v) atomicAdd(&hist[b * nb + k], v);
  }
}

// one wave per image: descending cumulative scan, find threshold bin
__global__ __launch_bounds__(64) void scan_kernel(int phase, const unsigned* __restrict__ hist,
                                                  Ctrl* __restrict__ ctrl) {
  const int b = blockIdx.x;
  const int lane = threadIdx.x;
  const int nb = (phase == 3) ? 256 : 4096;
  const int chunks = nb >> 6;
  const unsigned target = (phase == 1) ? 6000u : ((phase == 2) ? ctrl[b].rem1 : ctrl[b].rem2);
  const unsigned* h = hist + b * nb;
  const int topbin = nb - 1 - lane * chunks;
  unsigned mysum = 0;
  for (int c = 0; c < chunks; c++) mysum += h[topbin - c];
  unsigned cum = mysum;
  for (int off = 1; off < 64; off <<= 1) {
    const unsigned v = __shfl_up(cum, off, 64);
    if (lane >= off) cum += v;
  }
  const unsigned prev = cum - mysum;
  if (prev < target && cum >= target) {
    unsigned c2 = prev;
    for (int c = 0; c < chunks; c++) {
      const int bin = topbin - c;
      const unsigned hv = h[bin];
      if (c2 + hv >= target) {
        const unsigned rem = target - c2;
        if (phase == 1) { ctrl[b].t1 = (unsigned)bin; ctrl[b].rem1 = rem; }
        else if (phase == 2) { ctrl[b].t2 = (unsigned)bin; ctrl[b].rem2 = rem; }
        else {
          ctrl[b].thr = (ctrl[b].t1 << 20) | (ctrl[b].t2 << 8) | (unsigned)bin;
          ctrl[b].needEq = rem;
        }
        break;
      }
      c2 += hv;
    }
  }
}

__global__ __launch_bounds__(256) void compact_kernel(const float* __restrict__ probs, Ctrl* __restrict__ ctrl,
                                                      unsigned long long* __restrict__ sel,
                                                      unsigned* __restrict__ eqBuf, int N) {
  const int b = blockIdx.y;
  const unsigned THR = ctrl[b].thr;
  const int start = blockIdx.x * 4096;
  const int end = min(start + 4096, N);
  const int lane = threadIdx.x & 63;
  const int iters = (end - start + 255) / 256;
  for (int it = 0; it < iters; it++) {
    const int i = start + it * 256 + (int)threadIdx.x;
    const bool v = i < end;
    unsigned bits = 0u;
    if (v) bits = __float_as_uint(probs[(size_t)(b * N + i) * 2 + 1]);
    const bool gt = v && (bits > THR);
    const bool eq = v && (bits == THR);
    const unsigned long long mg = __ballot(gt);
    if (mg) {
      const int leader = __builtin_ctzll(mg);
      unsigned base = 0;
      if (lane == leader) base = atomicAdd(&ctrl[b].selCount, (unsigned)__builtin_popcountll(mg));
      base = (unsigned)__shfl((int)base, leader, 64);
      if (gt) {
        const int rank = __builtin_popcountll(mg & ((1ull << lane) - 1ull));
        const unsigned pos = base + (unsigned)rank;
        if (pos < (unsigned)KPAD) sel[b * KPAD + pos] = ((unsigned long long)bits << 32) | (unsigned)i;
      }
    }
    const unsigned long long me = __ballot(eq);
    if (me) {
      const int leader = __builtin_ctzll(me);
      unsigned base = 0;
      if (lane == leader) base = atomicAdd(&ctrl[b].eqCount, (unsigned)__builtin_popcountll(me));
      base = (unsigned)__shfl((int)base, leader, 64);
      if (eq) {
        const int rank = __builtin_popcountll(me & ((1ull << lane) - 1ull));
        const unsigned pos = base + (unsigned)rank;
        if (pos < (unsigned)EQCAP) eqBuf[b * EQCAP + pos] = (unsigned)i;
      }
    }
  }
}

// resolve ties at the exact threshold: take lowest indices
__global__ __launch_bounds__(256) void eqres_kernel(Ctrl* __restrict__ ctrl, const unsigned* __restrict__ eqBuf,
                                                    unsigned long long* __restrict__ sel) {
  __shared__ unsigned si[EQCAP];
  const int b = blockIdx.x;
  const unsigned need = ctrl[b].needEq;
  unsigned cnt = ctrl[b].eqCount; if (cnt > EQCAP) cnt = EQCAP;
  const unsigned base = ctrl[b].selCount;
  const unsigned long long thrHi = ((unsigned long long)ctrl[b].thr) << 32;
  if (cnt <= need) {
    for (unsigned e = threadIdx.x; e < cnt; e += 256)
      sel[b * KPAD + base + e] = thrHi | (unsigned long long)eqBuf[b * EQCAP + e];
    if (threadIdx.x == 0) ctrl[b].total = base + cnt;
  } else {
    for (int k = threadIdx.x; k < EQCAP; k += 256)
      si[k] = (k < (int)cnt) ? eqBuf[b * EQCAP + k] : 0xFFFFFFFFu;
    __syncthreads();
    for (int k = 2; k <= EQCAP; k <<= 1)
      for (int j = k >> 1; j > 0; j >>= 1) {
        for (int idx = threadIdx.x; idx < EQCAP; idx += 256) {
          const int p = idx ^ j;
          if (p > idx) {
            const unsigned a = si[idx], c = si[p];
            const bool up = ((idx & k) == 0);
            if ((a > c) == up) { si[idx] = c; si[p] = a; }
          }
        }
        __syncthreads();
      }
    for (unsigned e = threadIdx.x; e < need; e += 256)
      sel[b * KPAD + base + e] = thrHi | (unsigned long long)si[e];
    if (threadIdx.x == 0) ctrl[b].total = base + need;
  }
}

// Pairwise rank + fused decode. key = (scorebits<<32) | ~idx; rank = #{keys > mine}.
// 1D grid, b = blockIdx.x & 7 (XCD affinity: image b's boxes written from XCD b).
__global__ __launch_bounds__(256) void rank_kernel(const Ctrl* __restrict__ ctrl,
                                                   const unsigned long long* __restrict__ sel,
                                                   const float* __restrict__ anchors,
                                                   const float* __restrict__ bbox,
                                                   float4* __restrict__ boxes, int N) {
  const int b = blockIdx.x & 7;
  const int it = blockIdx.x >> 3;    // 0..93
  const int tid = threadIdx.x;
  const int wv = tid >> 6, lane = tid & 63;
  __shared__ unsigned long long skey[KPAD];   // 48128 B
  __shared__ unsigned scnt[4][64];
  int total = (int)ctrl[b].total; if (total > KSEL) total = KSEL;
  for (int i = tid; i < KPAD; i += 256) {
    unsigned long long kp = 0ull;
    if (i < total) {
      const unsigned long long e = sel[b * KPAD + i];
      kp = (e & 0xFFFFFFFF00000000ull) | (unsigned long long)(0xFFFFFFFFu - (unsigned)e);
    }
    skey[i] = kp;
  }
  __syncthreads();
  const int me = it * 64 + lane;               // < 6016
  const unsigned long long myk = skey[me];
  const int chunk = KPAD / 4;                  // 1504
  const int lo = wv * chunk;
  unsigned cnt = 0;
#pragma unroll 8
  for (int c = 0; c < chunk; ++c) cnt += (skey[lo + c] > myk) ? 1u : 0u;
  scnt[wv][lane] = cnt;
  __syncthreads();
  if (wv == 0 && me < total) {
    const unsigned rank = scnt[0][lane] + scnt[1][lane] + scnt[2][lane] + scnt[3][lane];
    unsigned idx = 0xFFFFFFFFu - (unsigned)myk;
    if (idx >= (unsigned)N) idx = 0;  // safety
    const float4 A = ((const float4*)anchors)[(size_t)b * N + idx];
    const float4 R = ((const float4*)bbox)[(size_t)b * N + idx];
    const float d0 = R.x * 0.1f, d1 = R.y * 0.1f, d2 = R.z * 0.2f, d3 = R.w * 0.2f;
    const float h = A.z - A.x;
    const float w = A.w - A.y;
    const float cy = A.x + 0.5f * h + d0 * h;
    const float cx = A.y + 0.5f * w + d1 * w;
    const float e2 = (float)exp((double)d2);  // correctly-rounded f32 exp
    const float e3 = (float)exp((double)d3);
    const float h2 = h * e2;
    const float w2 = w * e3;
    float y1 = cy - 0.5f * h2;
    float x1 = cx - 0.5f * w2;
    float y2 = y1 + h2;
    float x2 = x1 + w2;
    y1 = fminf(fmaxf(y1, 0.0f), 1.0f);
    x1 = fminf(fmaxf(x1, 0.0f), 1.0f);
    y2 = fminf(fmaxf(y2, 0.0f), 1.0f);
    x2 = fminf(fmaxf(x2, 0.0f), 1.0f);
    boxes[b * KPAD + rank] = make_float4(y1, x1, y2, x2);
  }
}

// ---- bitmatrix NMS ----
// Row-major storage: mat[((b*KPAD) + i)*NWORDS + w]. Upper triangle only; diagonal word has
// bits c <= i zeroed. 1D grid, b = blockIdx.x & 7 (XCD affinity with rank/resolve).
__global__ __launch_bounds__(256) void suppmat_kernel(const float4* __restrict__ boxes,
                                                      unsigned long long* __restrict__ mat) {
  const int b = blockIdx.x & 7;
  const int it = blockIdx.x >> 3;       // row tile 0..93
  const int wv = threadIdx.x >> 6;
  const int lane = threadIdx.x & 63;
  const float4* gbox = boxes + b * KPAD;
  __shared__ float4 srow[64];
  __shared__ float sarea[64];
  __shared__ unsigned long long wbuf[64][NWORDS];   // 48128 B
  if (threadIdx.x < 64) {
    const float4 v = gbox[it * 64 + threadIdx.x];
    srow[threadIdx.x] = v;
    sarea[threadIdx.x] = (v.z - v.x) * (v.w - v.y);
  }
  __syncthreads();
  float4 rb[16]; float rba[16];
#pragma unroll
  for (int k = 0; k < 16; ++k) { rb[k] = srow[wv * 16 + k]; rba[k] = sarea[wv * 16 + k]; }
  const double M = 0.7000000178813934326171875;
  for (int jt = it; jt < NWORDS; ++jt) {
    const int c = jt * 64 + lane;
    const float4 cv = gbox[c];
    const float ca = (cv.z - cv.x) * (cv.w - cv.y);
#pragma unroll
    for (int k = 0; k < 16; ++k) {
      const int i = it * 64 + wv * 16 + k;
      const float4 hb = rb[k];
      const float ha = rba[k];
      const float iy1 = fmaxf(hb.x, cv.x);
      const float ix1 = fmaxf(hb.y, cv.y);
      const float iy2 = fminf(hb.z, cv.z);
      const float ix2 = fminf(hb.w, cv.w);
      const float dy = fmaxf(iy2 - iy1, 0.0f);
      const float dx = fmaxf(ix2 - ix1, 0.0f);
      const float inter = dy * dx;
      const float denom = ha + ca - inter + 1e-12f;
      const bool s = (c > i) && ((double)inter >= M * (double)denom);
      const unsigned long long w = __ballot(s);
      if (lane == 0) wbuf[wv * 16 + k][jt] = w;
    }
  }
  __syncthreads();
  const int nw = NWORDS - it;
  unsigned long long* obase = mat + ((size_t)b * KPAD + (size_t)it * 64) * NWORDS;
  for (int q = threadIdx.x; q < 64 * nw; q += 256) {
    const int r = q / nw;
    const int k = q - r * nw;
    obase[(size_t)r * NWORDS + it + k] = wbuf[r][it + k];
  }
}

// Window-batched exact greedy resolve. One 768-thread block per image.
// Wave 0: parallel gather (popcount/prefix/select-bit) + shfl-based colmask + register replay.
// All waves: tail suppression (independent unrolled loads + LDS atomicAnd). 2 barriers/round.
__global__ __launch_bounds__(768) void resolve_kernel(const Ctrl* __restrict__ ctrl,
                                                      const float4* __restrict__ boxes,
                                                      const unsigned long long* __restrict__ mat,
                                                      float* __restrict__ out) {
  const int b = blockIdx.x;
  const int tid = threadIdx.x;
  const int lane = tid & 63;
  const int wv = tid >> 6;
  int total = (int)ctrl[b].total; if (total > KSEL) total = KSEL;
  const unsigned long long* cmat = mat + (size_t)b * KPAD * NWORDS;
  const float4* gbox = boxes + b * KPAD;
  float4* outv = (float4*)(out + (size_t)b * PROP * 4);

  __shared__ unsigned long long smask[NWORDS];
  __shared__ unsigned long long s_colmask[64];
  __shared__ int s_heads[64];
  __shared__ int s_cnt, s_nAcc, s_total, s_cursor, s_wlast;

  for (int k = tid; k < NWORDS; k += RT) {
    const int lo = k * 64;
    unsigned long long m = 0ull;
    if (lo < total) m = (total - lo >= 64) ? ~0ull : ((1ull << (total - lo)) - 1ull);
    smask[k] = m;
  }
  if (tid == 0) { s_total = 0; s_cursor = 0; }
  __syncthreads();

  for (;;) {
    if (wv == 0) {
      const int totalOld = s_total;
      // ---- parallel gather: find first nonempty word F >= cursor word ----
      int F = -1;
      {
        int Wc = s_cursor >> 6;
        while (Wc < NWORDS) {
          unsigned long long wl2 = 0ull;
          const int wi2 = Wc + lane;
          if (wi2 < NWORDS) wl2 = smask[wi2];
          const unsigned long long nzb = __ballot(wl2 != 0ull);
          if (nzb) { F = Wc + __builtin_ctzll(nzb); break; }
          Wc += 64;
        }
      }
      int cnt = 0, jlast = -1, na = 0;
      if (F >= 0) {
        // 8-word span from F: per-lane index assignment via popcount prefix + select-bit
        unsigned long long sw = 0ull;
        if (lane < 8 && F + lane < NWORDS) sw = smask[F + lane];
        const int pc = __popcll(sw);
        int pq[8];
#pragma unroll
        for (int q = 0; q < 8; ++q) pq[q] = __shfl(pc, q, 64);
        const int T = pq[0] + pq[1] + pq[2] + pq[3] + pq[4] + pq[5] + pq[6] + pq[7];
        cnt = (T < 64) ? T : 64;
        int rem = lane, ksel = 0;
#pragma unroll
        for (int q = 0; q < 8; ++q) {
          if (ksel == q && rem >= pq[q]) { rem -= pq[q]; ksel = q + 1; }
        }
        const unsigned long long wk = __shfl(sw, ksel & 7, 64);
        // select rem-th set bit of wk
        int pos = 0; int rr = rem;
        unsigned lo32 = (unsigned)wk;
        int c = __popc(lo32);
        if (rr >= c) { rr -= c; pos = 32; lo32 = (unsigned)(wk >> 32); }
        { const unsigned h = lo32 & 0xFFFFu; c = __popc(h); if (rr >= c) { rr -= c; pos += 16; lo32 >>= 16; } }
        { const unsigned h = lo32 & 0xFFu;  c = __popc(h); if (rr >= c) { rr -= c; pos += 8;  lo32 >>= 8; } }
        { const unsigned h = lo32 & 0xFu;   c = __popc(h); if (rr >= c) { rr -= c; pos += 4;  lo32 >>= 4; } }
        { const unsigned h = lo32 & 0x3u;   c = __popc(h); if (rr >= c) { rr -= c; pos += 2;  lo32 >>= 2; } }
        { const unsigned h = lo32 & 0x1u;   if (rr >= (int)h) pos += 1; }
        const int jme = ((F + (ksel & 7)) << 6) | pos;   // valid for lane < cnt
        jlast = __shfl(jme, cnt - 1, 64);
        const int jj = (lane < cnt) ? jme : (F << 6);    // safe for loads
        // ---- window row loads (8 contiguous words) ----
        const unsigned long long* rp = cmat + (size_t)jj * NWORDS;
        unsigned long long rw[8];
#pragma unroll
        for (int k = 0; k < 8; ++k)
          rw[k] = (F + k < NWORDS) ? rp[F + k] : 0ull;
        // ---- colmask via shfl of packed (rel,bit) ----
        const int rb = (((jj >> 6) - F) << 6) | (jj & 63);
        unsigned long long colmask = 0ull;
#pragma unroll
        for (int i = 0; i < 64; ++i) {
          const int rbm = __shfl(rb, i, 64);
          const int rel = rbm >> 6, bit = rbm & 63;
          unsigned long long x = rw[0];
          x = (rel == 1) ? rw[1] : x;
          x = (rel == 2) ? rw[2] : x;
          x = (rel == 3) ? rw[3] : x;
          x = (rel == 4) ? rw[4] : x;
          x = (rel == 5) ? rw[5] : x;
          x = (rel == 6) ? rw[6] : x;
          x = (rel == 7) ? rw[7] : x;
          colmask |= ((x >> bit) & 1ull) << i;
        }
        colmask = (lane < 63) ? (colmask & (~0ull << (lane + 1))) : 0ull;  // strictly upper
        if (lane >= cnt) colmask = 0ull;
        if (cnt < 64) colmask &= ((1ull << cnt) - 1ull);
        s_colmask[lane] = colmask;
        // ---- greedy replay (registers + unrolled LDS reads) ----
        unsigned long long aliveW = (cnt >= 64) ? ~0ull : ((1ull << cnt) - 1ull);
        unsigned long long acc = 0ull;
#pragma unroll
        for (int i = 0; i < 64; ++i) {
          const unsigned long long cm = s_colmask[i];
          const unsigned long long take = 0ull - ((aliveW >> i) & 1ull);
          acc |= (1ull << i) & take;
          aliveW &= ~(cm & take);
        }
        // budget truncation: keep earliest
        const int need = PROP - totalOld;
        na = __popcll(acc);
        if (na > need) {
          unsigned long long t2 = acc, a2 = 0ull;
          for (int c2 = 0; c2 < need; ++c2) { a2 |= t2 & (0ull - t2); t2 &= t2 - 1ull; }
          acc = a2; na = need;
        }
        if (lane < cnt && ((acc >> lane) & 1ull)) {
          const int r = __popcll(acc & ((1ull << lane) - 1ull));
          outv[totalOld + r] = gbox[jme];
          s_heads[r] = jme;
        }
        if (lane == 0) {
          // range-clear: everything <= jlast is resolved (selected or suppressed)
          const int wl2 = jlast >> 6;
          for (int w = F; w < wl2; ++w) smask[w] = 0ull;
          const unsigned long long keep = ((jlast & 63) == 63) ? 0ull : (~0ull << ((jlast & 63) + 1));
          smask[wl2] &= keep;
          s_cursor = jlast + 1;
        }
      }
      if (lane == 0) { s_cnt = cnt; s_nAcc = na; s_total = totalOld + na; s_wlast = jlast; }
    }
    __syncthreads();  // B2
    if (s_cnt == 0) break;
    if (s_total >= PROP) break;
    // ---- tail suppression: (word, 8-row-group) per thread; 8 independent loads each ----
    const int na2 = s_nAcc;
    const int wT = s_wlast >> 6;
    const int nw = NWORDS - wT;
    if (tid < (nw << 3)) {
      const int w = wT + (tid >> 3);
      const int g = tid & 7;
      unsigned long long orv = 0ull;
#pragma unroll
      for (int k = 0; k < 8; ++k) {
        const int r = g + (k << 3);
        const unsigned long long rv = cmat[(size_t)s_heads[(r < na2) ? r : 0] * NWORDS + w];
        orv |= (r < na2) ? rv : 0ull;
      }
      if (orv) atomicAnd(&smask[w], ~orv);
    }
    __syncthreads();  // B3
  }

  const int wtot = s_total;
  for (int k = wtot + tid; k < PROP; k += RT) outv[k] = make_float4(0.f, 0.f, 0.f, 0.f);
}

// ---- fallback windowed NMS (round-2, known-passing) for small ws ----
__global__ __launch_bounds__(1024) void nms_kernel(const float4* __restrict__ boxes, float* __restrict__ out) {
  const int b = blockIdx.x;
  const int tid = threadIdx.x;
  const int lane = tid & 63;
  const float4* gbox = boxes + b * KPAD;
  float* outB = out + b * (PROP * 4);
  __shared__ unsigned long long smask[94];
  __shared__ int s_widx[64];
  __shared__ float4 s_wbox[64];
  __shared__ float s_wha[64];
  __shared__ int s_cnt, s_nAcc, s_total, s_cursor;
  for (int k = tid; k < 94; k += 1024)
    smask[k] = (k == 93) ? ((1ull << 48) - 1ull) : ~0ull;
  if (tid == 0) { s_cursor = 0; s_total = 0; }
  __syncthreads();
  const double M = 0.7000000178813934326171875;
  for (int round = 0; round < PROP; ++round) {
    if (tid == 0) {
      int cnt = 0;
      const int cur = s_cursor;
      int w = cur >> 6;
      unsigned long long word = (w < 94) ? (smask[w] & (~0ull << (cur & 63))) : 0ull;
      while (cnt < 64) {
        while (word == 0ull && ++w < 94) word = smask[w];
        if (w >= 94) break;
        const int bit = __builtin_ctzll(word);
        word &= word - 1ull;
        s_widx[cnt++] = (w << 6) | bit;
      }
      s_cnt = cnt;
      s_cursor = cnt ? (s_widx[cnt - 1] + 1) : KSEL;
    }
    __syncthreads();
    const int cnt = s_cnt;
    const int tailStart = s_cursor;
    if (cnt == 0) break;
    if (tid < 64) {
      const int j = (lane < cnt) ? s_widx[lane] : -1;
      float4 v = make_float4(0.f, 0.f, 0.f, 0.f);
      if (j >= 0) v = gbox[j];
      const float a = (v.z - v.x) * (v.w - v.y);
      const int totalOld = s_total;
      unsigned long long aliveW = __ballot(j >= 0);
      unsigned long long acc = 0ull;
      for (int i = 0; i < 64; ++i) {
        const float hx = __shfl(v.x, i), hy = __shfl(v.y, i);
        const float hz = __shfl(v.z, i), hw = __shfl(v.w, i);
        const float ha = __shfl(a, i);
        bool s = false;
        if (j >= 0 && lane > i) {
          const float iy1 = fmaxf(hx, v.x);
          const float ix1 = fmaxf(hy, v.y);
          const float iy2 = fminf(hz, v.z);
          const float ix2 = fminf(hw, v.w);
          const float dy = fmaxf(iy2 - iy1, 0.0f);
          const float dx = fmaxf(ix2 - ix1, 0.0f);
          const float inter = dy * dx;
          const float denom = ha + a - inter + 1e-12f;
          s = ((double)inter >= M * (double)denom);
        }
        const unsigned long long m = __ballot(s);
        if (aliveW & (1ull << i)) { acc |= 1ull << i; aliveW &= ~m; }
      }
      const int need = PROP - totalOld;
      int na = __popcll(acc);
      if (na > need) {
        unsigned long long t = acc, a2 = 0ull;
        for (int c2 = 0; c2 < need; ++c2) { a2 |= t & (0ull - t); t &= t - 1ull; }
        acc = a2; na = need;
      }
      if ((acc >> lane) & 1ull) {
        const int r = __popcll(acc & ((1ull << lane) - 1ull));
        float* o = outB + (size_t)(totalOld + r) * 4;
        o[0] = v.x; o[1] = v.y; o[2] = v.z; o[3] = v.w;
        s_wbox[r] = v; s_wha[r] = a;
      }
      if (lane == 0) { s_nAcc = na; s_total = totalOld + na; }
      if (j >= 0) atomicAnd(&smask[j >> 6], ~(1ull << (j & 63)));
    }
    __syncthreads();
    const int total = s_total;
    const int nAcc = s_nAcc;
    if (total >= PROP) break;
    for (int j = tailStart + tid; j < KSEL; j += 1024) {
      if (!((smask[j >> 6] >> (j & 63)) & 1ull)) continue;
      const float4 v = gbox[j];
      const float a = (v.z - v.x) * (v.w - v.y);
      bool supp = false;
      for (int r = 0; r < nAcc; ++r) {
        const float4 hb = s_wbox[r];
        const float ha = s_wha[r];
        const float iy1 = fmaxf(hb.x, v.x);
        const float ix1 = fmaxf(hb.y, v.y);
        const float iy2 = fminf(hb.z, v.z);
        const float ix2 = fminf(hb.w, v.w);
        const float dy = fmaxf(iy2 - iy1, 0.0f);
        const float dx = fmaxf(ix2 - ix1, 0.0f);
        const float inter = dy * dx;
        const float denom = ha + a - inter + 1e-12f;
        if ((double)inter >= M * (double)denom) { supp = true; break; }
      }
      if (supp) atomicAnd(&smask[j >> 6], ~(1ull << (j & 63)));
    }
    __syncthreads();
  }
  const int written = s_total;
  for (int u = written * 4 + tid; u < PROP * 4; u += 1024) outB[u] = 0.0f;
}

extern "C" void kernel_launch(void* const* d_in, const int* in_sizes, int n_in,
                              void* d_out, int out_size, void* d_ws, size_t ws_size,
                              hipStream_t stream) {
  (void)n_in; (void)out_size;
  const float* probs = (const float*)d_in[0];
  const float* bbox = (const float*)d_in[1];
  const float* anchors = (const float*)d_in[2];
  float* out = (float*)d_out;
  char* ws = (char*)d_ws;
  const int N = in_sizes[0] / (NB * 2);  // 261888

  unsigned* hist1 = (unsigned*)(ws + OFF_HIST1);
  unsigned* hist2 = (unsigned*)(ws + OFF_HIST2);
  unsigned* hist3 = (unsigned*)(ws + OFF_HIST3);
  Ctrl* ctrl = (Ctrl*)(ws + OFF_CTRL);
  unsigned long long* sel = (unsigned long long*)(ws + OFF_SEL);
  unsigned* eqBuf = (unsigned*)(ws + OFF_EQ);
  float4* boxes = (float4*)(ws + OFF_BOX);
  unsigned long long* mat = (unsigned long long*)(ws + OFF_MAT);

  const int zeroN = (int)(OFF_SEL / 4);  // hist1+hist2+hist3+ctrl
  zero_kernel<<<dim3((zeroN + 255) / 256), dim3(256), 0, stream>>>((unsigned*)ws, zeroN);

  const int gx = (N + 4095) / 4096;      // 64
  hist_kernel<<<dim3(gx, NB), dim3(256), 0, stream>>>(1, probs, hist1, ctrl, N);
  scan_kernel<<<dim3(NB), dim3(64), 0, stream>>>(1, hist1, ctrl);
  hist_kernel<<<dim3(gx, NB), dim3(256), 0, stream>>>(2, probs, hist2, ctrl, N);
  scan_kernel<<<dim3(NB), dim3(64), 0, stream>>>(2, hist2, ctrl);
  hist_kernel<<<dim3(gx, NB), dim3(256), 0, stream>>>(3, probs, hist3, ctrl, N);
  scan_kernel<<<dim3(NB), dim3(64), 0, stream>>>(3, hist3, ctrl);
  compact_kernel<<<dim3(gx, NB), dim3(256), 0, stream>>>(probs, ctrl, sel, eqBuf, N);
  eqres_kernel<<<dim3(NB), dim3(256), 0, stream>>>(ctrl, eqBuf, sel);
  rank_kernel<<<dim3(NTILE * NB), dim3(256), 0, stream>>>(ctrl, sel, anchors, bbox, boxes, N);

  if (ws_size >= (size_t)OFF_MAT + MAT_BYTES) {
    suppmat_kernel<<<dim3(NTILE * NB), dim3(256), 0, stream>>>(boxes, mat);
    resolve_kernel<<<dim3(NB), dim3(768), 0, stream>>>(ctrl, boxes, mat, out);
  } else {
    nms_kernel<<<dim3(NB), dim3(1024), 0, stream>>>(boxes, out);
  }
}